// Round 1
// baseline (8443.401 us; speedup 1.0000x reference)
//
#include <hip/hip_runtime.h>

#define NF 128   // hidden feature width
#define BM 64    // gemm row tile
#define KC 32    // gemm k chunk

// ---------------- init: deg=1 (self loop), zero mean accumulator -------------
__global__ void init_kernel(float* degf, float* gsum, int n) {
    int i = blockIdx.x * blockDim.x + threadIdx.x;
    if (i < n) degf[i] = 1.0f;
    if (i < NF) gsum[i] = 0.0f;
}

__global__ void deg_count_kernel(const int* __restrict__ dst, float* degf, int E) {
    int e = blockIdx.x * blockDim.x + threadIdx.x;
    if (e < E) atomicAdd(&degf[dst[e]], 1.0f);
}

__global__ void dis_kernel(const float* __restrict__ degf, float* dis, float* dis2, int n) {
    int i = blockIdx.x * blockDim.x + threadIdx.x;
    if (i >= n) return;
    float d = degf[i];
    dis[i]  = 1.0f / sqrtf(d);
    dis2[i] = 1.0f / d;
}

// ---------------- embedding: h = x[n,16] @ W[16,128] + b ---------------------
__global__ __launch_bounds__(256) void emb_gemm(const float* __restrict__ x,
                                                const float* __restrict__ W,
                                                const float* __restrict__ b,
                                                float* __restrict__ h, int n) {
    int tid = threadIdx.x;
    int col = tid & (NF - 1);
    int row = blockIdx.x * 2 + (tid >> 7);
    if (row >= n) return;
    const float* xr = x + (size_t)row * 16;
    float acc = b[col];
#pragma unroll
    for (int k = 0; k < 16; ++k) acc = fmaf(xr[k], W[k * NF + col], acc);
    h[(size_t)row * NF + col] = acc;
}

// ---------------- conv GEMM: hW = relu?(A) @ W; agg = hW*dis2 + bias ---------
__global__ __launch_bounds__(256) void conv_gemm(const float* __restrict__ A,
                                                 const float* __restrict__ W,
                                                 const float* __restrict__ bias,
                                                 const float* __restrict__ dis2,
                                                 float* __restrict__ hW,
                                                 float* __restrict__ agg,
                                                 int n, int relu_in) {
    __shared__ float sW[KC][NF];
    __shared__ float sA[BM][36];   // 36 stride: 16B-aligned float4 stores, 2-way-max bank alias
    int tid = threadIdx.x;
    int row0 = blockIdx.x * BM;
    int ty = tid >> 4;            // 0..15 -> 4 rows each
    int tx = tid & 15;            // 0..15 -> 8 cols each
    int r0 = ty * 4;
    int c0 = tx * 8;
    float acc[4][8] = {};

    for (int kc = 0; kc < NF; kc += KC) {
        // stage W chunk [KC][128]: 16 floats/thread, coalesced
        {
            int idx = tid * 16;
            int kr = idx >> 7;
            int cc = idx & (NF - 1);
            const float4* s4 = (const float4*)&W[(size_t)(kc + kr) * NF + cc];
            float4* d4 = (float4*)&sW[kr][cc];
            d4[0] = s4[0]; d4[1] = s4[1]; d4[2] = s4[2]; d4[3] = s4[3];
        }
        // stage A chunk [BM][KC]: 8 floats/thread
        {
            int idx = tid * 8;
            int r = idx >> 5;
            int c = idx & 31;
            int grow = row0 + r;
            float4 v0 = {0.f,0.f,0.f,0.f}, v1 = {0.f,0.f,0.f,0.f};
            if (grow < n) {
                const float4* s4 = (const float4*)&A[(size_t)grow * NF + kc + c];
                v0 = s4[0]; v1 = s4[1];
                if (relu_in) {
                    v0.x = fmaxf(v0.x, 0.f); v0.y = fmaxf(v0.y, 0.f);
                    v0.z = fmaxf(v0.z, 0.f); v0.w = fmaxf(v0.w, 0.f);
                    v1.x = fmaxf(v1.x, 0.f); v1.y = fmaxf(v1.y, 0.f);
                    v1.z = fmaxf(v1.z, 0.f); v1.w = fmaxf(v1.w, 0.f);
                }
            }
            float* d = &sA[r][c];
            *(float4*)(d)     = v0;
            *(float4*)(d + 4) = v1;
        }
        __syncthreads();
#pragma unroll
        for (int k = 0; k < KC; ++k) {
            float a[4];
#pragma unroll
            for (int i = 0; i < 4; ++i) a[i] = sA[r0 + i][k];
            float wv[8];
#pragma unroll
            for (int j = 0; j < 8; ++j) wv[j] = sW[k][c0 + j];
#pragma unroll
            for (int i = 0; i < 4; ++i)
#pragma unroll
                for (int j = 0; j < 8; ++j)
                    acc[i][j] = fmaf(a[i], wv[j], acc[i][j]);
        }
        __syncthreads();
    }

    float bc[8];
#pragma unroll
    for (int j = 0; j < 8; ++j) bc[j] = bias[c0 + j];

#pragma unroll
    for (int i = 0; i < 4; ++i) {
        int grow = row0 + r0 + i;
        if (grow < n) {
            float d2 = dis2[grow];
            float4 h0 = { acc[i][0], acc[i][1], acc[i][2], acc[i][3] };
            float4 h1 = { acc[i][4], acc[i][5], acc[i][6], acc[i][7] };
            float4* hw4 = (float4*)&hW[(size_t)grow * NF + c0];
            hw4[0] = h0; hw4[1] = h1;
            float4 g0 = { fmaf(acc[i][0], d2, bc[0]), fmaf(acc[i][1], d2, bc[1]),
                          fmaf(acc[i][2], d2, bc[2]), fmaf(acc[i][3], d2, bc[3]) };
            float4 g1 = { fmaf(acc[i][4], d2, bc[4]), fmaf(acc[i][5], d2, bc[5]),
                          fmaf(acc[i][6], d2, bc[6]), fmaf(acc[i][7], d2, bc[7]) };
            float4* ag4 = (float4*)&agg[(size_t)grow * NF + c0];
            ag4[0] = g0; ag4[1] = g1;
        }
    }
}

// ---------------- edge scatter: agg[dst] += hW[src] * dis[src]*dis[dst] ------
__global__ __launch_bounds__(256) void scatter_kernel(const int* __restrict__ src,
                                                      const int* __restrict__ dst,
                                                      const float* __restrict__ dis,
                                                      const float* __restrict__ hW,
                                                      float* __restrict__ agg, int E) {
    long gid = (long)blockIdx.x * blockDim.x + threadIdx.x;
    int e = (int)(gid >> 5);
    int q = (int)(gid & 31);
    if (e >= E) return;
    int s = src[e], d = dst[e];
    float coef = dis[s] * dis[d];
    float4 v = ((const float4*)hW)[(size_t)s * 32 + q];
    float* o = agg + (size_t)d * NF + q * 4;
    atomicAdd(o + 0, v.x * coef);
    atomicAdd(o + 1, v.y * coef);
    atomicAdd(o + 2, v.z * coef);
    atomicAdd(o + 3, v.w * coef);
}

// ---------------- mean over nodes of relu(agg) -------------------------------
__global__ __launch_bounds__(256) void mean_kernel(const float* __restrict__ agg,
                                                   float* gsum, int n) {
    int col = threadIdx.x & (NF - 1);
    int rlane = threadIdx.x >> 7;  // 0..1
    float s = 0.f;
    for (int row = blockIdx.x * 2 + rlane; row < n; row += gridDim.x * 2)
        s += fmaxf(agg[(size_t)row * NF + col], 0.f);
    __shared__ float red[256];
    red[threadIdx.x] = s;
    __syncthreads();
    if (rlane == 0) atomicAdd(&gsum[col], s + red[threadIdx.x + 128]);
}

// ---------------- head: mean -> fc1+relu -> fc2 ------------------------------
__global__ __launch_bounds__(128) void head_kernel(const float* __restrict__ gsum,
                                                   const float* __restrict__ fc1_w,
                                                   const float* __restrict__ fc1_b,
                                                   const float* __restrict__ fc2_w,
                                                   const float* __restrict__ fc2_b,
                                                   float* __restrict__ out, int n) {
    __shared__ float gm[NF], h1[NF];
    int t = threadIdx.x;
    gm[t] = gsum[t] / (float)n;
    __syncthreads();
    float acc = fc1_b[t];
    for (int k = 0; k < NF; ++k) acc = fmaf(gm[k], fc1_w[k * NF + t], acc);
    h1[t] = fmaxf(acc, 0.f);
    __syncthreads();
    if (t < 64) {
        float o = fc2_b[t];
        for (int k = 0; k < NF; ++k) o = fmaf(h1[k], fc2_w[k * 64 + t], o);
        out[t] = o;
    }
}

extern "C" void kernel_launch(void* const* d_in, const int* in_sizes, int n_in,
                              void* d_out, int out_size, void* d_ws, size_t ws_size,
                              hipStream_t stream) {
    const float* x      = (const float*)d_in[0];
    const int*   ei     = (const int*)  d_in[1];
    const float* emb_w  = (const float*)d_in[2];
    const float* emb_b  = (const float*)d_in[3];
    const float* conv_w = (const float*)d_in[4];
    const float* conv_b = (const float*)d_in[5];
    const float* fc1_w  = (const float*)d_in[6];
    const float* fc1_b  = (const float*)d_in[7];
    const float* fc2_w  = (const float*)d_in[8];
    const float* fc2_b  = (const float*)d_in[9];
    float* out = (float*)d_out;

    int n = in_sizes[0] / 16;
    int E = in_sizes[1] / 2;
    const int* srcI = ei;
    const int* dstI = ei + E;

    // workspace carve-up
    char* w = (char*)d_ws;
    size_t bufBytes = ((size_t)n * NF * sizeof(float) + 255) & ~(size_t)255;
    size_t vecBytes = ((size_t)n * sizeof(float) + 255) & ~(size_t)255;
    float* buf0 = (float*)w; w += bufBytes;
    float* buf1 = (float*)w; w += bufBytes;
    float* buf2 = (float*)w; w += bufBytes;
    float* degf = (float*)w; w += vecBytes;
    float* dis  = (float*)w; w += vecBytes;
    float* dis2 = (float*)w; w += vecBytes;
    float* gsum = (float*)w; w += 256;

    int nb256 = (n + 255) / 256;
    init_kernel<<<nb256, 256, 0, stream>>>(degf, gsum, n);
    deg_count_kernel<<<(E + 255) / 256, 256, 0, stream>>>(dstI, degf, E);
    dis_kernel<<<nb256, 256, 0, stream>>>(degf, dis, dis2, n);

    // embedding
    emb_gemm<<<(n + 1) / 2, 256, 0, stream>>>(x, emb_w, emb_b, buf0, n);

    int gemm_grid = (n + BM - 1) / BM;
    long sthreads = (long)E * 32;
    int sgrid = (int)((sthreads + 255) / 256);

    // layer 0: A=buf0 -> hW=buf1, agg=buf2
    conv_gemm<<<gemm_grid, 256, 0, stream>>>(buf0, conv_w, conv_b, dis2,
                                             buf1, buf2, n, 0);
    scatter_kernel<<<sgrid, 256, 0, stream>>>(srcI, dstI, dis, buf1, buf2, E);

    // layer 1: A=relu(buf2) -> hW=buf1, agg=buf0
    conv_gemm<<<gemm_grid, 256, 0, stream>>>(buf2, conv_w + 1 * NF * NF, conv_b + 1 * NF,
                                             dis2, buf1, buf0, n, 1);
    scatter_kernel<<<sgrid, 256, 0, stream>>>(srcI, dstI, dis, buf1, buf0, E);

    // layer 2: A=relu(buf0) -> hW=buf1, agg=buf2
    conv_gemm<<<gemm_grid, 256, 0, stream>>>(buf0, conv_w + 2 * NF * NF, conv_b + 2 * NF,
                                             dis2, buf1, buf2, n, 1);
    scatter_kernel<<<sgrid, 256, 0, stream>>>(srcI, dstI, dis, buf1, buf2, E);

    // global mean of relu(buf2), then MLP head
    mean_kernel<<<512, 256, 0, stream>>>(buf2, gsum, n);
    head_kernel<<<1, 128, 0, stream>>>(gsum, fc1_w, fc1_b, fc2_w, fc2_b, out, n);
}

// Round 2
// 905.984 us; speedup vs baseline: 9.3196x; 9.3196x over previous
//
#include <hip/hip_runtime.h>

#define NF 128   // hidden feature width
#define BM 64    // gemm row tile
#define KC 32    // gemm k chunk

// ---------------- init: zero int-degree histogram + mean accumulator ---------
__global__ void init_kernel(int* cnt, float* gsum, int n) {
    int i = blockIdx.x * blockDim.x + threadIdx.x;
    if (i < n) cnt[i] = 0;
    if (i < NF) gsum[i] = 0.0f;
}

__global__ void deg_hist_kernel(const int* __restrict__ dst, int* cnt, int E) {
    int e = blockIdx.x * blockDim.x + threadIdx.x;
    if (e < E) atomicAdd(&cnt[dst[e]], 1);
}

__global__ void dis_kernel(const int* __restrict__ cnt, float* dis, float* dis2, int n) {
    int i = blockIdx.x * blockDim.x + threadIdx.x;
    if (i >= n) return;
    float d = (float)(cnt[i] + 1);   // +1 self-loop
    dis[i]  = 1.0f / sqrtf(d);
    dis2[i] = 1.0f / d;
}

// ---------------- prefix scan (3 phases) for CSR offsets ---------------------
__global__ void scan1_kernel(const int* __restrict__ cnt, int* excl, int* bsum, int n) {
    __shared__ int s[256];
    int t = threadIdx.x;
    int i = blockIdx.x * 256 + t;
    int v = (i < n) ? cnt[i] : 0;
    s[t] = v;
    __syncthreads();
    for (int off = 1; off < 256; off <<= 1) {
        int add = (t >= off) ? s[t - off] : 0;
        __syncthreads();
        s[t] += add;
        __syncthreads();
    }
    if (i < n) excl[i] = s[t] - v;     // exclusive scan within block
    if (t == 255) bsum[blockIdx.x] = s[255];
}

__global__ void scan2_kernel(int* bsum, int nb) {
    __shared__ int s[512];
    int t = threadIdx.x;
    int v = (t < nb) ? bsum[t] : 0;
    s[t] = v;
    __syncthreads();
    for (int off = 1; off < 512; off <<= 1) {
        int add = (t >= off) ? s[t - off] : 0;
        __syncthreads();
        s[t] += add;
        __syncthreads();
    }
    if (t < nb) bsum[t] = s[t] - v;    // exclusive block offsets
}

__global__ void scan3_kernel(int* excl, int* cursor, const int* __restrict__ bsum, int n) {
    int i = blockIdx.x * blockDim.x + threadIdx.x;
    if (i >= n) return;
    int o = excl[i] + bsum[blockIdx.x * 256 / 256 >= 0 ? i / 256 : 0];  // i/256
    excl[i] = o;
    cursor[i] = o;
}

__global__ void fill_kernel(const int* __restrict__ src, const int* __restrict__ dst,
                            int* cursor, int* csr_src, int E) {
    int e = blockIdx.x * blockDim.x + threadIdx.x;
    if (e >= E) return;
    int d = dst[e];
    int p = atomicAdd(&cursor[d], 1);
    csr_src[p] = src[e];
}

// ---------------- embedding: h = x[n,16] @ W[16,128] + b ---------------------
__global__ __launch_bounds__(256) void emb_gemm(const float* __restrict__ x,
                                                const float* __restrict__ W,
                                                const float* __restrict__ b,
                                                float* __restrict__ h, int n) {
    int tid = threadIdx.x;
    int col = tid & (NF - 1);
    int row = blockIdx.x * 2 + (tid >> 7);
    if (row >= n) return;
    const float* xr = x + (size_t)row * 16;
    float acc = b[col];
#pragma unroll
    for (int k = 0; k < 16; ++k) acc = fmaf(xr[k], W[k * NF + col], acc);
    h[(size_t)row * NF + col] = acc;
}

// ---------------- conv GEMM: hW = relu?(A) @ W -------------------------------
__global__ __launch_bounds__(256) void conv_gemm(const float* __restrict__ A,
                                                 const float* __restrict__ W,
                                                 float* __restrict__ hW,
                                                 int n, int relu_in) {
    __shared__ float sW[KC][NF];
    __shared__ float sA[BM][36];
    int tid = threadIdx.x;
    int row0 = blockIdx.x * BM;
    int ty = tid >> 4;
    int tx = tid & 15;
    int r0 = ty * 4;
    int c0 = tx * 8;
    float acc[4][8] = {};

    for (int kc = 0; kc < NF; kc += KC) {
        {
            int idx = tid * 16;
            int kr = idx >> 7;
            int cc = idx & (NF - 1);
            const float4* s4 = (const float4*)&W[(size_t)(kc + kr) * NF + cc];
            float4* d4 = (float4*)&sW[kr][cc];
            d4[0] = s4[0]; d4[1] = s4[1]; d4[2] = s4[2]; d4[3] = s4[3];
        }
        {
            int idx = tid * 8;
            int r = idx >> 5;
            int c = idx & 31;
            int grow = row0 + r;
            float4 v0 = {0.f,0.f,0.f,0.f}, v1 = {0.f,0.f,0.f,0.f};
            if (grow < n) {
                const float4* s4 = (const float4*)&A[(size_t)grow * NF + kc + c];
                v0 = s4[0]; v1 = s4[1];
                if (relu_in) {
                    v0.x = fmaxf(v0.x, 0.f); v0.y = fmaxf(v0.y, 0.f);
                    v0.z = fmaxf(v0.z, 0.f); v0.w = fmaxf(v0.w, 0.f);
                    v1.x = fmaxf(v1.x, 0.f); v1.y = fmaxf(v1.y, 0.f);
                    v1.z = fmaxf(v1.z, 0.f); v1.w = fmaxf(v1.w, 0.f);
                }
            }
            float* d = &sA[r][c];
            *(float4*)(d)     = v0;
            *(float4*)(d + 4) = v1;
        }
        __syncthreads();
#pragma unroll
        for (int k = 0; k < KC; ++k) {
            float a[4];
#pragma unroll
            for (int i = 0; i < 4; ++i) a[i] = sA[r0 + i][k];
            float wv[8];
#pragma unroll
            for (int j = 0; j < 8; ++j) wv[j] = sW[k][c0 + j];
#pragma unroll
            for (int i = 0; i < 4; ++i)
#pragma unroll
                for (int j = 0; j < 8; ++j)
                    acc[i][j] = fmaf(a[i], wv[j], acc[i][j]);
        }
        __syncthreads();
    }

#pragma unroll
    for (int i = 0; i < 4; ++i) {
        int grow = row0 + r0 + i;
        if (grow < n) {
            float4 h0 = { acc[i][0], acc[i][1], acc[i][2], acc[i][3] };
            float4 h1 = { acc[i][4], acc[i][5], acc[i][6], acc[i][7] };
            float4* hw4 = (float4*)&hW[(size_t)grow * NF + c0];
            hw4[0] = h0; hw4[1] = h1;
        }
    }
}

// -------- gather aggregate: out[d] = dis[d]*sum_e dis[s]*hW[s] + dis2[d]*hW[d] + bias
// one 64-lane wave per node, float2 per lane (128 floats)
__global__ __launch_bounds__(256) void gather_agg(const int* __restrict__ csr_src,
                                                  const int* __restrict__ off,
                                                  const int* __restrict__ cnt,
                                                  const float* __restrict__ dis,
                                                  const float* __restrict__ dis2,
                                                  const float* __restrict__ hW,
                                                  const float* __restrict__ bias,
                                                  float* __restrict__ outv, int n) {
    int t = threadIdx.x & 63;
    int d = blockIdx.x * 4 + (threadIdx.x >> 6);
    if (d >= n) return;
    int o = off[d];
    int c = cnt[d];
    const float2* hw2 = (const float2*)hW;
    float2 acc = {0.f, 0.f};
    int j = 0;
    for (; j + 1 < c; j += 2) {          // 2-way unroll: two row-loads in flight
        int s0 = csr_src[o + j];
        int s1 = csr_src[o + j + 1];
        float w0 = dis[s0], w1 = dis[s1];
        float2 v0 = hw2[(size_t)s0 * 64 + t];
        float2 v1 = hw2[(size_t)s1 * 64 + t];
        acc.x = fmaf(v0.x, w0, acc.x); acc.y = fmaf(v0.y, w0, acc.y);
        acc.x = fmaf(v1.x, w1, acc.x); acc.y = fmaf(v1.y, w1, acc.y);
    }
    if (j < c) {
        int s0 = csr_src[o + j];
        float w0 = dis[s0];
        float2 v0 = hw2[(size_t)s0 * 64 + t];
        acc.x = fmaf(v0.x, w0, acc.x); acc.y = fmaf(v0.y, w0, acc.y);
    }
    float dd = dis[d], d2 = dis2[d];
    float2 self = hw2[(size_t)d * 64 + t];
    float2 b2 = ((const float2*)bias)[t];
    float2 o2;
    o2.x = fmaf(acc.x, dd, fmaf(self.x, d2, b2.x));
    o2.y = fmaf(acc.y, dd, fmaf(self.y, d2, b2.y));
    ((float2*)outv)[(size_t)d * 64 + t] = o2;
}

// ---------------- mean over nodes of relu(agg) -------------------------------
__global__ __launch_bounds__(256) void mean_kernel(const float* __restrict__ agg,
                                                   float* gsum, int n) {
    int col = threadIdx.x & (NF - 1);
    int rlane = threadIdx.x >> 7;
    float s = 0.f;
    for (int row = blockIdx.x * 2 + rlane; row < n; row += gridDim.x * 2)
        s += fmaxf(agg[(size_t)row * NF + col], 0.f);
    __shared__ float red[256];
    red[threadIdx.x] = s;
    __syncthreads();
    if (rlane == 0) atomicAdd(&gsum[col], s + red[threadIdx.x + 128]);
}

// ---------------- head: mean -> fc1+relu -> fc2 ------------------------------
__global__ __launch_bounds__(128) void head_kernel(const float* __restrict__ gsum,
                                                   const float* __restrict__ fc1_w,
                                                   const float* __restrict__ fc1_b,
                                                   const float* __restrict__ fc2_w,
                                                   const float* __restrict__ fc2_b,
                                                   float* __restrict__ out, int n) {
    __shared__ float gm[NF], h1[NF];
    int t = threadIdx.x;
    gm[t] = gsum[t] / (float)n;
    __syncthreads();
    float acc = fc1_b[t];
    for (int k = 0; k < NF; ++k) acc = fmaf(gm[k], fc1_w[k * NF + t], acc);
    h1[t] = fmaxf(acc, 0.f);
    __syncthreads();
    if (t < 64) {
        float o = fc2_b[t];
        for (int k = 0; k < NF; ++k) o = fmaf(h1[k], fc2_w[k * 64 + t], o);
        out[t] = o;
    }
}

extern "C" void kernel_launch(void* const* d_in, const int* in_sizes, int n_in,
                              void* d_out, int out_size, void* d_ws, size_t ws_size,
                              hipStream_t stream) {
    const float* x      = (const float*)d_in[0];
    const int*   ei     = (const int*)  d_in[1];
    const float* emb_w  = (const float*)d_in[2];
    const float* emb_b  = (const float*)d_in[3];
    const float* conv_w = (const float*)d_in[4];
    const float* conv_b = (const float*)d_in[5];
    const float* fc1_w  = (const float*)d_in[6];
    const float* fc1_b  = (const float*)d_in[7];
    const float* fc2_w  = (const float*)d_in[8];
    const float* fc2_b  = (const float*)d_in[9];
    float* out = (float*)d_out;

    int n = in_sizes[0] / 16;
    int E = in_sizes[1] / 2;
    const int* srcI = ei;
    const int* dstI = ei + E;

    // workspace carve-up
    char* w = (char*)d_ws;
    size_t bufBytes = ((size_t)n * NF * sizeof(float) + 255) & ~(size_t)255;
    size_t vecBytes = ((size_t)n * sizeof(float) + 255) & ~(size_t)255;
    float* buf0 = (float*)w; w += bufBytes;
    float* buf1 = (float*)w; w += bufBytes;
    float* buf2 = (float*)w; w += bufBytes;
    float* dis  = (float*)w; w += vecBytes;
    float* dis2 = (float*)w; w += vecBytes;
    float* gsum = (float*)w; w += 256;
    int* cnt    = (int*)w;   w += vecBytes;
    int* excl   = (int*)w;   w += vecBytes;
    int* cursor = (int*)w;   w += vecBytes;
    int* bsum   = (int*)w;   w += 2048;
    int* csr_src= (int*)w;   w += ((size_t)E * sizeof(int) + 255) & ~(size_t)255;

    int nb256 = (n + 255) / 256;   // 391 blocks -> fits scan2's 512
    int eb256 = (E + 255) / 256;

    // CSR build
    init_kernel<<<nb256, 256, 0, stream>>>(cnt, gsum, n);
    deg_hist_kernel<<<eb256, 256, 0, stream>>>(dstI, cnt, E);
    dis_kernel<<<nb256, 256, 0, stream>>>(cnt, dis, dis2, n);
    scan1_kernel<<<nb256, 256, 0, stream>>>(cnt, excl, bsum, n);
    scan2_kernel<<<1, 512, 0, stream>>>(bsum, nb256);
    scan3_kernel<<<nb256, 256, 0, stream>>>(excl, cursor, bsum, n);
    fill_kernel<<<eb256, 256, 0, stream>>>(srcI, dstI, cursor, csr_src, E);

    // embedding
    emb_gemm<<<(n + 1) / 2, 256, 0, stream>>>(x, emb_w, emb_b, buf0, n);

    int gemm_grid = (n + BM - 1) / BM;
    int agg_grid = (n + 3) / 4;

    // layer 0
    conv_gemm<<<gemm_grid, 256, 0, stream>>>(buf0, conv_w, buf1, n, 0);
    gather_agg<<<agg_grid, 256, 0, stream>>>(csr_src, excl, cnt, dis, dis2,
                                             buf1, conv_b, buf2, n);
    // layer 1
    conv_gemm<<<gemm_grid, 256, 0, stream>>>(buf2, conv_w + 1 * NF * NF, buf1, n, 1);
    gather_agg<<<agg_grid, 256, 0, stream>>>(csr_src, excl, cnt, dis, dis2,
                                             buf1, conv_b + 1 * NF, buf0, n);
    // layer 2
    conv_gemm<<<gemm_grid, 256, 0, stream>>>(buf0, conv_w + 2 * NF * NF, buf1, n, 1);
    gather_agg<<<agg_grid, 256, 0, stream>>>(csr_src, excl, cnt, dis, dis2,
                                             buf1, conv_b + 2 * NF, buf2, n);

    // global mean of relu(buf2), then MLP head
    mean_kernel<<<512, 256, 0, stream>>>(buf2, gsum, n);
    head_kernel<<<1, 128, 0, stream>>>(gsum, fc1_w, fc1_b, fc2_w, fc2_b, out, n);
}

// Round 3
// 846.030 us; speedup vs baseline: 9.9800x; 1.0709x over previous
//
#include <hip/hip_runtime.h>

#define NF 128   // hidden feature width
#define BM 64    // gemm row tile
#define KC 32    // gemm k chunk
#define SA 68    // sAT row stride (floats): 272 B = 16B-aligned, conflict-free b128 reads

// ---------------- init: zero int-degree histogram + mean accumulator ---------
__global__ void init_kernel(int* cnt, float* gsum, int n) {
    int i = blockIdx.x * blockDim.x + threadIdx.x;
    if (i < n) cnt[i] = 0;
    if (i < NF) gsum[i] = 0.0f;
}

// XCD-partitioned histogram: group p (= blockIdx&7 -> XCD p) handles dst range p
__global__ __launch_bounds__(256) void deg_hist_kernel(const int* __restrict__ dst,
                                                       int* cnt, int E, int n) {
    int p = blockIdx.x & 7;
    int lo = (int)((long)p * n / 8);
    int hi = (int)((long)(p + 1) * n / 8);
    int stride = (gridDim.x >> 3) * 256;
    for (int e = (blockIdx.x >> 3) * 256 + threadIdx.x; e < E; e += stride) {
        int d = dst[e];
        if (d >= lo && d < hi) atomicAdd(&cnt[d], 1);
    }
}

__global__ void dis_kernel(const int* __restrict__ cnt, float* dis, float* dis2, int n) {
    int i = blockIdx.x * blockDim.x + threadIdx.x;
    if (i >= n) return;
    float d = (float)(cnt[i] + 1);   // +1 self-loop
    dis[i]  = 1.0f / sqrtf(d);
    dis2[i] = 1.0f / d;
}

// ---------------- prefix scan (3 phases) for CSR offsets ---------------------
__global__ void scan1_kernel(const int* __restrict__ cnt, int* excl, int* bsum, int n) {
    __shared__ int s[256];
    int t = threadIdx.x;
    int i = blockIdx.x * 256 + t;
    int v = (i < n) ? cnt[i] : 0;
    s[t] = v;
    __syncthreads();
    for (int off = 1; off < 256; off <<= 1) {
        int add = (t >= off) ? s[t - off] : 0;
        __syncthreads();
        s[t] += add;
        __syncthreads();
    }
    if (i < n) excl[i] = s[t] - v;
    if (t == 255) bsum[blockIdx.x] = s[255];
}

__global__ void scan2_kernel(int* bsum, int nb) {
    __shared__ int s[512];
    int t = threadIdx.x;
    int v = (t < nb) ? bsum[t] : 0;
    s[t] = v;
    __syncthreads();
    for (int off = 1; off < 512; off <<= 1) {
        int add = (t >= off) ? s[t - off] : 0;
        __syncthreads();
        s[t] += add;
        __syncthreads();
    }
    if (t < nb) bsum[t] = s[t] - v;
}

__global__ void scan3_kernel(int* excl, int* cursor, const int* __restrict__ bsum, int n) {
    int i = blockIdx.x * blockDim.x + threadIdx.x;
    if (i >= n) return;
    int o = excl[i] + bsum[i >> 8];
    excl[i] = o;
    cursor[i] = o;
}

// XCD-partitioned CSR fill: group p writes only csr positions of dst range p,
// so each 64B line of csr_src is completed within one XCD's L2 (dense writeback)
__global__ __launch_bounds__(256) void fill_kernel(const int* __restrict__ src,
                                                   const int* __restrict__ dst,
                                                   int* cursor, int* csr_src,
                                                   int E, int n) {
    int p = blockIdx.x & 7;
    int lo = (int)((long)p * n / 8);
    int hi = (int)((long)(p + 1) * n / 8);
    int stride = (gridDim.x >> 3) * 256;
    for (int e = (blockIdx.x >> 3) * 256 + threadIdx.x; e < E; e += stride) {
        int d = dst[e];
        if (d >= lo && d < hi) {
            int pos = atomicAdd(&cursor[d], 1);
            csr_src[pos] = src[e];
        }
    }
}

// ---------------- embedding: h = x[n,16] @ W[16,128] + b ---------------------
__global__ __launch_bounds__(256) void emb_gemm(const float* __restrict__ x,
                                                const float* __restrict__ W,
                                                const float* __restrict__ b,
                                                float* __restrict__ h, int n) {
    int tid = threadIdx.x;
    int col = tid & (NF - 1);
    int row = blockIdx.x * 2 + (tid >> 7);
    if (row >= n) return;
    const float* xr = x + (size_t)row * 16;
    float acc = b[col];
#pragma unroll
    for (int k = 0; k < 16; ++k) acc = fmaf(xr[k], W[k * NF + col], acc);
    h[(size_t)row * NF + col] = acc;
}

// ---------------- conv GEMM: hW = relu?(A) @ W -------------------------------
// A staged TRANSPOSED (sAT[k][r]) so fragment loads are ds_read_b128
__global__ __launch_bounds__(256) void conv_gemm(const float* __restrict__ A,
                                                 const float* __restrict__ W,
                                                 float* __restrict__ hW,
                                                 int n, int relu_in) {
    __shared__ float sW[KC][NF];
    __shared__ float sAT[KC][SA];
    int tid = threadIdx.x;
    int row0 = blockIdx.x * BM;
    int ty = tid >> 4;            // 0..15 -> 4 rows each
    int tx = tid & 15;            // 0..15 -> 8 cols each
    int r0 = ty * 4;
    int c0 = tx * 8;
    float acc[4][8] = {};

    for (int kc = 0; kc < NF; kc += KC) {
        // stage W chunk [KC][128]: 16 floats/thread, coalesced
        {
            int idx = tid * 16;
            int kr = idx >> 7;
            int cc = idx & (NF - 1);
            const float4* s4 = (const float4*)&W[(size_t)(kc + kr) * NF + cc];
            float4* d4 = (float4*)&sW[kr][cc];
            d4[0] = s4[0]; d4[1] = s4[1]; d4[2] = s4[2]; d4[3] = s4[3];
        }
        // stage A chunk transposed: thread loads row r, cols c..c+7, writes sAT[c+j][r]
        {
            int r = tid >> 2;             // 0..63
            int c = (tid & 3) * 8;        // 0,8,16,24
            int grow = row0 + r;
            float v[8] = {};
            if (grow < n) {
                const float4* s4 = (const float4*)&A[(size_t)grow * NF + kc + c];
                float4 v0 = s4[0], v1 = s4[1];
                v[0]=v0.x; v[1]=v0.y; v[2]=v0.z; v[3]=v0.w;
                v[4]=v1.x; v[5]=v1.y; v[6]=v1.z; v[7]=v1.w;
                if (relu_in) {
#pragma unroll
                    for (int j = 0; j < 8; ++j) v[j] = fmaxf(v[j], 0.f);
                }
            }
#pragma unroll
            for (int j = 0; j < 8; ++j) sAT[c + j][r] = v[j];
        }
        __syncthreads();
#pragma unroll 4
        for (int k = 0; k < KC; ++k) {
            float4 av = *(const float4*)&sAT[k][r0];
            float4 w0 = *(const float4*)&sW[k][c0];
            float4 w1 = *(const float4*)&sW[k][c0 + 4];
            float a[4] = { av.x, av.y, av.z, av.w };
            float wv[8] = { w0.x, w0.y, w0.z, w0.w, w1.x, w1.y, w1.z, w1.w };
#pragma unroll
            for (int i = 0; i < 4; ++i)
#pragma unroll
                for (int j = 0; j < 8; ++j)
                    acc[i][j] = fmaf(a[i], wv[j], acc[i][j]);
        }
        __syncthreads();
    }

#pragma unroll
    for (int i = 0; i < 4; ++i) {
        int grow = row0 + r0 + i;
        if (grow < n) {
            float4 h0 = { acc[i][0], acc[i][1], acc[i][2], acc[i][3] };
            float4 h1 = { acc[i][4], acc[i][5], acc[i][6], acc[i][7] };
            float4* hw4 = (float4*)&hW[(size_t)grow * NF + c0];
            hw4[0] = h0; hw4[1] = h1;
        }
    }
}

// -------- gather aggregate: out[d] = dis[d]*sum_e dis[s]*hW[s] + dis2[d]*hW[d] + bias
// one wave per node; 32 lanes x float4 per row; 2 halves process alternating edges;
// 2-deep unroll per half -> 4 row-loads in flight per wave
__global__ __launch_bounds__(256) void gather_agg(const int* __restrict__ csr_src,
                                                  const int* __restrict__ off,
                                                  const int* __restrict__ cnt,
                                                  const float* __restrict__ dis,
                                                  const float* __restrict__ dis2,
                                                  const float* __restrict__ hW,
                                                  const float* __restrict__ bias,
                                                  float* __restrict__ outv, int n) {
    int lane = threadIdx.x & 63;
    int half = lane >> 5;
    int li = lane & 31;
    int d = blockIdx.x * 4 + (threadIdx.x >> 6);
    if (d >= n) return;
    int o = off[d];
    int c = cnt[d];
    const float4* hw4 = (const float4*)hW;
    float4 acc = {0.f, 0.f, 0.f, 0.f};
    int j = half;
    for (; j + 6 < c; j += 8) {     // 4 edges of this half in flight
        int s0 = csr_src[o + j];
        int s1 = csr_src[o + j + 2];
        int s2 = csr_src[o + j + 4];
        int s3 = csr_src[o + j + 6];
        float w0 = dis[s0], w1 = dis[s1], w2 = dis[s2], w3 = dis[s3];
        float4 v0 = hw4[(size_t)s0 * 32 + li];
        float4 v1 = hw4[(size_t)s1 * 32 + li];
        float4 v2 = hw4[(size_t)s2 * 32 + li];
        float4 v3 = hw4[(size_t)s3 * 32 + li];
        acc.x = fmaf(v0.x, w0, acc.x); acc.y = fmaf(v0.y, w0, acc.y);
        acc.z = fmaf(v0.z, w0, acc.z); acc.w = fmaf(v0.w, w0, acc.w);
        acc.x = fmaf(v1.x, w1, acc.x); acc.y = fmaf(v1.y, w1, acc.y);
        acc.z = fmaf(v1.z, w1, acc.z); acc.w = fmaf(v1.w, w1, acc.w);
        acc.x = fmaf(v2.x, w2, acc.x); acc.y = fmaf(v2.y, w2, acc.y);
        acc.z = fmaf(v2.z, w2, acc.z); acc.w = fmaf(v2.w, w2, acc.w);
        acc.x = fmaf(v3.x, w3, acc.x); acc.y = fmaf(v3.y, w3, acc.y);
        acc.z = fmaf(v3.z, w3, acc.z); acc.w = fmaf(v3.w, w3, acc.w);
    }
    for (; j < c; j += 2) {
        int s0 = csr_src[o + j];
        float w0 = dis[s0];
        float4 v0 = hw4[(size_t)s0 * 32 + li];
        acc.x = fmaf(v0.x, w0, acc.x); acc.y = fmaf(v0.y, w0, acc.y);
        acc.z = fmaf(v0.z, w0, acc.z); acc.w = fmaf(v0.w, w0, acc.w);
    }
    // combine the two halves' partial sums
    acc.x += __shfl_xor(acc.x, 32);
    acc.y += __shfl_xor(acc.y, 32);
    acc.z += __shfl_xor(acc.z, 32);
    acc.w += __shfl_xor(acc.w, 32);
    if (half == 0) {
        float dd = dis[d], d2 = dis2[d];
        float4 self = hw4[(size_t)d * 32 + li];
        float4 b4 = ((const float4*)bias)[li];
        float4 o4;
        o4.x = fmaf(acc.x, dd, fmaf(self.x, d2, b4.x));
        o4.y = fmaf(acc.y, dd, fmaf(self.y, d2, b4.y));
        o4.z = fmaf(acc.z, dd, fmaf(self.z, d2, b4.z));
        o4.w = fmaf(acc.w, dd, fmaf(self.w, d2, b4.w));
        ((float4*)outv)[(size_t)d * 32 + li] = o4;
    }
}

// ---------------- mean over nodes of relu(agg) -------------------------------
__global__ __launch_bounds__(256) void mean_kernel(const float* __restrict__ agg,
                                                   float* gsum, int n) {
    int col = threadIdx.x & (NF - 1);
    int rlane = threadIdx.x >> 7;
    float s = 0.f;
    for (int row = blockIdx.x * 2 + rlane; row < n; row += gridDim.x * 2)
        s += fmaxf(agg[(size_t)row * NF + col], 0.f);
    __shared__ float red[256];
    red[threadIdx.x] = s;
    __syncthreads();
    if (rlane == 0) atomicAdd(&gsum[col], s + red[threadIdx.x + 128]);
}

// ---------------- head: mean -> fc1+relu -> fc2 ------------------------------
__global__ __launch_bounds__(128) void head_kernel(const float* __restrict__ gsum,
                                                   const float* __restrict__ fc1_w,
                                                   const float* __restrict__ fc1_b,
                                                   const float* __restrict__ fc2_w,
                                                   const float* __restrict__ fc2_b,
                                                   float* __restrict__ out, int n) {
    __shared__ float gm[NF], h1[NF];
    int t = threadIdx.x;
    gm[t] = gsum[t] / (float)n;
    __syncthreads();
    float acc = fc1_b[t];
    for (int k = 0; k < NF; ++k) acc = fmaf(gm[k], fc1_w[k * NF + t], acc);
    h1[t] = fmaxf(acc, 0.f);
    __syncthreads();
    if (t < 64) {
        float o = fc2_b[t];
        for (int k = 0; k < NF; ++k) o = fmaf(h1[k], fc2_w[k * 64 + t], o);
        out[t] = o;
    }
}

extern "C" void kernel_launch(void* const* d_in, const int* in_sizes, int n_in,
                              void* d_out, int out_size, void* d_ws, size_t ws_size,
                              hipStream_t stream) {
    const float* x      = (const float*)d_in[0];
    const int*   ei     = (const int*)  d_in[1];
    const float* emb_w  = (const float*)d_in[2];
    const float* emb_b  = (const float*)d_in[3];
    const float* conv_w = (const float*)d_in[4];
    const float* conv_b = (const float*)d_in[5];
    const float* fc1_w  = (const float*)d_in[6];
    const float* fc1_b  = (const float*)d_in[7];
    const float* fc2_w  = (const float*)d_in[8];
    const float* fc2_b  = (const float*)d_in[9];
    float* out = (float*)d_out;

    int n = in_sizes[0] / 16;
    int E = in_sizes[1] / 2;
    const int* srcI = ei;
    const int* dstI = ei + E;

    // workspace carve-up
    char* w = (char*)d_ws;
    size_t bufBytes = ((size_t)n * NF * sizeof(float) + 255) & ~(size_t)255;
    size_t vecBytes = ((size_t)n * sizeof(float) + 255) & ~(size_t)255;
    float* buf0 = (float*)w; w += bufBytes;
    float* buf1 = (float*)w; w += bufBytes;
    float* buf2 = (float*)w; w += bufBytes;
    float* dis  = (float*)w; w += vecBytes;
    float* dis2 = (float*)w; w += vecBytes;
    float* gsum = (float*)w; w += 256;
    int* cnt    = (int*)w;   w += vecBytes;
    int* excl   = (int*)w;   w += vecBytes;
    int* cursor = (int*)w;   w += vecBytes;
    int* bsum   = (int*)w;   w += 2048;
    int* csr_src= (int*)w;   w += ((size_t)E * sizeof(int) + 255) & ~(size_t)255;

    int nb256 = (n + 255) / 256;

    // CSR build (XCD-partitioned hist + fill)
    init_kernel<<<nb256, 256, 0, stream>>>(cnt, gsum, n);
    deg_hist_kernel<<<1024, 256, 0, stream>>>(dstI, cnt, E, n);
    dis_kernel<<<nb256, 256, 0, stream>>>(cnt, dis, dis2, n);
    scan1_kernel<<<nb256, 256, 0, stream>>>(cnt, excl, bsum, n);
    scan2_kernel<<<1, 512, 0, stream>>>(bsum, nb256);
    scan3_kernel<<<nb256, 256, 0, stream>>>(excl, cursor, bsum, n);
    fill_kernel<<<1024, 256, 0, stream>>>(srcI, dstI, cursor, csr_src, E, n);

    // embedding
    emb_gemm<<<(n + 1) / 2, 256, 0, stream>>>(x, emb_w, emb_b, buf0, n);

    int gemm_grid = (n + BM - 1) / BM;
    int agg_grid = (n + 3) / 4;

    // layer 0
    conv_gemm<<<gemm_grid, 256, 0, stream>>>(buf0, conv_w, buf1, n, 0);
    gather_agg<<<agg_grid, 256, 0, stream>>>(csr_src, excl, cnt, dis, dis2,
                                             buf1, conv_b, buf2, n);
    // layer 1
    conv_gemm<<<gemm_grid, 256, 0, stream>>>(buf2, conv_w + 1 * NF * NF, buf1, n, 1);
    gather_agg<<<agg_grid, 256, 0, stream>>>(csr_src, excl, cnt, dis, dis2,
                                             buf1, conv_b + 1 * NF, buf0, n);
    // layer 2
    conv_gemm<<<gemm_grid, 256, 0, stream>>>(buf0, conv_w + 2 * NF * NF, buf1, n, 1);
    gather_agg<<<agg_grid, 256, 0, stream>>>(csr_src, excl, cnt, dis, dis2,
                                             buf1, conv_b + 2 * NF, buf2, n);

    // global mean of relu(buf2), then MLP head
    mean_kernel<<<512, 256, 0, stream>>>(buf2, gsum, n);
    head_kernel<<<1, 128, 0, stream>>>(gsum, fc1_w, fc1_b, fc2_w, fc2_b, out, n);
}

// Round 4
// 695.435 us; speedup vs baseline: 12.1412x; 1.2165x over previous
//
#include <hip/hip_runtime.h>

#define NF 128   // hidden feature width
#define BM 64    // gemm row tile
#define KC 32    // gemm k chunk
#define SA 68    // sAT row stride (floats): 272 B = 16B-aligned, conflict-free b128 reads

// pack two fp32 -> two bf16 (RNE) in one uint (lo in low half)
__device__ __forceinline__ unsigned pack2bf(float lo, float hi) {
    unsigned a = __float_as_uint(lo);
    a = (a + 0x7FFFu + ((a >> 16) & 1u)) >> 16;
    unsigned b = __float_as_uint(hi);
    b = (b + 0x7FFFu + ((b >> 16) & 1u)) & 0xFFFF0000u;
    return a | b;
}

// unpack 8 bf16 from uint4, fma into acc[8] with weight w
__device__ __forceinline__ void bf8_fma(uint4 u, float w, float* acc) {
    acc[0] = fmaf(__uint_as_float(u.x << 16), w, acc[0]);
    acc[1] = fmaf(__uint_as_float(u.x & 0xFFFF0000u), w, acc[1]);
    acc[2] = fmaf(__uint_as_float(u.y << 16), w, acc[2]);
    acc[3] = fmaf(__uint_as_float(u.y & 0xFFFF0000u), w, acc[3]);
    acc[4] = fmaf(__uint_as_float(u.z << 16), w, acc[4]);
    acc[5] = fmaf(__uint_as_float(u.z & 0xFFFF0000u), w, acc[5]);
    acc[6] = fmaf(__uint_as_float(u.w << 16), w, acc[6]);
    acc[7] = fmaf(__uint_as_float(u.w & 0xFFFF0000u), w, acc[7]);
}

// ---------------- init: zero int-degree histogram + mean accumulator ---------
__global__ void init_kernel(int* cnt, float* gsum, int n) {
    int i = blockIdx.x * blockDim.x + threadIdx.x;
    if (i < n) cnt[i] = 0;
    if (i < NF) gsum[i] = 0.0f;
}

// XCD-partitioned histogram: group p (= blockIdx&7 -> XCD p) handles dst range p
__global__ __launch_bounds__(256) void deg_hist_kernel(const int* __restrict__ dst,
                                                       int* cnt, int E, int n) {
    int p = blockIdx.x & 7;
    int lo = (int)((long)p * n / 8);
    int hi = (int)((long)(p + 1) * n / 8);
    int stride = (gridDim.x >> 3) * 256;
    for (int e = (blockIdx.x >> 3) * 256 + threadIdx.x; e < E; e += stride) {
        int d = dst[e];
        if (d >= lo && d < hi) atomicAdd(&cnt[d], 1);
    }
}

__global__ void dis_kernel(const int* __restrict__ cnt, float* dis, float* dis2, int n) {
    int i = blockIdx.x * blockDim.x + threadIdx.x;
    if (i >= n) return;
    float d = (float)(cnt[i] + 1);   // +1 self-loop
    dis[i]  = 1.0f / sqrtf(d);
    dis2[i] = 1.0f / d;
}

// ---------------- prefix scan (3 phases) for CSR offsets ---------------------
__global__ void scan1_kernel(const int* __restrict__ cnt, int* excl, int* bsum, int n) {
    __shared__ int s[256];
    int t = threadIdx.x;
    int i = blockIdx.x * 256 + t;
    int v = (i < n) ? cnt[i] : 0;
    s[t] = v;
    __syncthreads();
    for (int off = 1; off < 256; off <<= 1) {
        int add = (t >= off) ? s[t - off] : 0;
        __syncthreads();
        s[t] += add;
        __syncthreads();
    }
    if (i < n) excl[i] = s[t] - v;
    if (t == 255) bsum[blockIdx.x] = s[255];
}

__global__ void scan2_kernel(int* bsum, int nb) {
    __shared__ int s[512];
    int t = threadIdx.x;
    int v = (t < nb) ? bsum[t] : 0;
    s[t] = v;
    __syncthreads();
    for (int off = 1; off < 512; off <<= 1) {
        int add = (t >= off) ? s[t - off] : 0;
        __syncthreads();
        s[t] += add;
        __syncthreads();
    }
    if (t < nb) bsum[t] = s[t] - v;
}

__global__ void scan3_kernel(int* excl, int* cursor, const int* __restrict__ bsum, int n) {
    int i = blockIdx.x * blockDim.x + threadIdx.x;
    if (i >= n) return;
    int o = excl[i] + bsum[i >> 8];
    excl[i] = o;
    cursor[i] = o;
}

// XCD-partitioned CSR fill
__global__ __launch_bounds__(256) void fill_kernel(const int* __restrict__ src,
                                                   const int* __restrict__ dst,
                                                   int* cursor, int* csr_src,
                                                   int E, int n) {
    int p = blockIdx.x & 7;
    int lo = (int)((long)p * n / 8);
    int hi = (int)((long)(p + 1) * n / 8);
    int stride = (gridDim.x >> 3) * 256;
    for (int e = (blockIdx.x >> 3) * 256 + threadIdx.x; e < E; e += stride) {
        int d = dst[e];
        if (d >= lo && d < hi) {
            int pos = atomicAdd(&cursor[d], 1);
            csr_src[pos] = src[e];
        }
    }
}

// ---------------- embedding: h = x[n,16] @ W[16,128] + b ---------------------
__global__ __launch_bounds__(256) void emb_gemm(const float* __restrict__ x,
                                                const float* __restrict__ W,
                                                const float* __restrict__ b,
                                                float* __restrict__ h, int n) {
    int tid = threadIdx.x;
    int col = tid & (NF - 1);
    int row = blockIdx.x * 2 + (tid >> 7);
    if (row >= n) return;
    const float* xr = x + (size_t)row * 16;
    float acc = b[col];
#pragma unroll
    for (int k = 0; k < 16; ++k) acc = fmaf(xr[k], W[k * NF + col], acc);
    h[(size_t)row * NF + col] = acc;
}

// ---------------- conv GEMM: hW(bf16) = relu?(A_fp32) @ W --------------------
__global__ __launch_bounds__(256) void conv_gemm(const float* __restrict__ A,
                                                 const float* __restrict__ W,
                                                 unsigned short* __restrict__ hWb,
                                                 int n, int relu_in) {
    __shared__ float sW[KC][NF];
    __shared__ float sAT[KC][SA];
    int tid = threadIdx.x;
    int row0 = blockIdx.x * BM;
    int ty = tid >> 4;            // 0..15 -> 4 rows each
    int tx = tid & 15;            // 0..15 -> 8 cols each
    int r0 = ty * 4;
    int c0 = tx * 8;
    float acc[4][8] = {};

    for (int kc = 0; kc < NF; kc += KC) {
        // stage W chunk [KC][128]
        {
            int idx = tid * 16;
            int kr = idx >> 7;
            int cc = idx & (NF - 1);
            const float4* s4 = (const float4*)&W[(size_t)(kc + kr) * NF + cc];
            float4* d4 = (float4*)&sW[kr][cc];
            d4[0] = s4[0]; d4[1] = s4[1]; d4[2] = s4[2]; d4[3] = s4[3];
        }
        // stage A chunk transposed
        {
            int r = tid >> 2;             // 0..63
            int c = (tid & 3) * 8;        // 0,8,16,24
            int grow = row0 + r;
            float v[8] = {};
            if (grow < n) {
                const float4* s4 = (const float4*)&A[(size_t)grow * NF + kc + c];
                float4 v0 = s4[0], v1 = s4[1];
                v[0]=v0.x; v[1]=v0.y; v[2]=v0.z; v[3]=v0.w;
                v[4]=v1.x; v[5]=v1.y; v[6]=v1.z; v[7]=v1.w;
                if (relu_in) {
#pragma unroll
                    for (int j = 0; j < 8; ++j) v[j] = fmaxf(v[j], 0.f);
                }
            }
#pragma unroll
            for (int j = 0; j < 8; ++j) sAT[c + j][r] = v[j];
        }
        __syncthreads();
#pragma unroll 4
        for (int k = 0; k < KC; ++k) {
            float4 av = *(const float4*)&sAT[k][r0];
            float4 w0 = *(const float4*)&sW[k][c0];
            float4 w1 = *(const float4*)&sW[k][c0 + 4];
            float a[4] = { av.x, av.y, av.z, av.w };
            float wv[8] = { w0.x, w0.y, w0.z, w0.w, w1.x, w1.y, w1.z, w1.w };
#pragma unroll
            for (int i = 0; i < 4; ++i)
#pragma unroll
                for (int j = 0; j < 8; ++j)
                    acc[i][j] = fmaf(a[i], wv[j], acc[i][j]);
        }
        __syncthreads();
    }

#pragma unroll
    for (int i = 0; i < 4; ++i) {
        int grow = row0 + r0 + i;
        if (grow < n) {
            uint4 p;
            p.x = pack2bf(acc[i][0], acc[i][1]);
            p.y = pack2bf(acc[i][2], acc[i][3]);
            p.z = pack2bf(acc[i][4], acc[i][5]);
            p.w = pack2bf(acc[i][6], acc[i][7]);
            *(uint4*)&hWb[(size_t)grow * NF + c0] = p;
        }
    }
}

// -------- gather aggregate over bf16 hW rows (256B = 16 lanes x uint4) -------
// one wave per node; quarter-wave per row; 4 quarters x 2-deep unroll = 8 rows in flight
__global__ __launch_bounds__(256) void gather_agg(const int* __restrict__ csr_src,
                                                  const int* __restrict__ off,
                                                  const int* __restrict__ cnt,
                                                  const float* __restrict__ dis,
                                                  const float* __restrict__ dis2,
                                                  const unsigned short* __restrict__ hWb,
                                                  const float* __restrict__ bias,
                                                  float* __restrict__ outv, int n) {
    int lane = threadIdx.x & 63;
    int q = lane >> 4;        // quarter 0..3
    int li = lane & 15;       // lane-in-quarter: features [li*8, li*8+8)
    int d = blockIdx.x * 4 + (threadIdx.x >> 6);
    if (d >= n) return;
    int o = off[d];
    int c = cnt[d];
    const uint4* hw = (const uint4*)hWb;   // row = 16 x uint4
    float acc[8] = {};
    int j = q;
    for (; j + 4 < c; j += 8) {
        int s0 = csr_src[o + j];
        int s1 = csr_src[o + j + 4];
        float w0 = dis[s0], w1 = dis[s1];
        uint4 u0 = hw[(size_t)s0 * 16 + li];
        uint4 u1 = hw[(size_t)s1 * 16 + li];
        bf8_fma(u0, w0, acc);
        bf8_fma(u1, w1, acc);
    }
    for (; j < c; j += 4) {
        int s0 = csr_src[o + j];
        float w0 = dis[s0];
        uint4 u0 = hw[(size_t)s0 * 16 + li];
        bf8_fma(u0, w0, acc);
    }
    // combine quarters
#pragma unroll
    for (int k = 0; k < 8; ++k) {
        acc[k] += __shfl_xor(acc[k], 16);
        acc[k] += __shfl_xor(acc[k], 32);
    }
    if (q == 0) {
        float dd = dis[d], d2 = dis2[d];
        uint4 us = hw[(size_t)d * 16 + li];
        float self[8] = {};
        bf8_fma(us, 1.0f, self);
        const float4* b4 = (const float4*)&bias[li * 8];
        float4 ba = b4[0], bb = b4[1];
        float bk[8] = { ba.x, ba.y, ba.z, ba.w, bb.x, bb.y, bb.z, bb.w };
        float4 o0, o1;
        o0.x = fmaf(acc[0], dd, fmaf(self[0], d2, bk[0]));
        o0.y = fmaf(acc[1], dd, fmaf(self[1], d2, bk[1]));
        o0.z = fmaf(acc[2], dd, fmaf(self[2], d2, bk[2]));
        o0.w = fmaf(acc[3], dd, fmaf(self[3], d2, bk[3]));
        o1.x = fmaf(acc[4], dd, fmaf(self[4], d2, bk[4]));
        o1.y = fmaf(acc[5], dd, fmaf(self[5], d2, bk[5]));
        o1.z = fmaf(acc[6], dd, fmaf(self[6], d2, bk[6]));
        o1.w = fmaf(acc[7], dd, fmaf(self[7], d2, bk[7]));
        float4* op = (float4*)&outv[(size_t)d * NF + li * 8];
        op[0] = o0;
        op[1] = o1;
    }
}

// ---------------- mean over nodes of relu(agg) -------------------------------
__global__ __launch_bounds__(256) void mean_kernel(const float* __restrict__ agg,
                                                   float* gsum, int n) {
    int col = threadIdx.x & (NF - 1);
    int rlane = threadIdx.x >> 7;
    float s = 0.f;
    for (int row = blockIdx.x * 2 + rlane; row < n; row += gridDim.x * 2)
        s += fmaxf(agg[(size_t)row * NF + col], 0.f);
    __shared__ float red[256];
    red[threadIdx.x] = s;
    __syncthreads();
    if (rlane == 0) atomicAdd(&gsum[col], s + red[threadIdx.x + 128]);
}

// ---------------- head: mean -> fc1+relu -> fc2 ------------------------------
__global__ __launch_bounds__(128) void head_kernel(const float* __restrict__ gsum,
                                                   const float* __restrict__ fc1_w,
                                                   const float* __restrict__ fc1_b,
                                                   const float* __restrict__ fc2_w,
                                                   const float* __restrict__ fc2_b,
                                                   float* __restrict__ out, int n) {
    __shared__ float gm[NF], h1[NF];
    int t = threadIdx.x;
    gm[t] = gsum[t] / (float)n;
    __syncthreads();
    float acc = fc1_b[t];
    for (int k = 0; k < NF; ++k) acc = fmaf(gm[k], fc1_w[k * NF + t], acc);
    h1[t] = fmaxf(acc, 0.f);
    __syncthreads();
    if (t < 64) {
        float o = fc2_b[t];
        for (int k = 0; k < NF; ++k) o = fmaf(h1[k], fc2_w[k * 64 + t], o);
        out[t] = o;
    }
}

extern "C" void kernel_launch(void* const* d_in, const int* in_sizes, int n_in,
                              void* d_out, int out_size, void* d_ws, size_t ws_size,
                              hipStream_t stream) {
    const float* x      = (const float*)d_in[0];
    const int*   ei     = (const int*)  d_in[1];
    const float* emb_w  = (const float*)d_in[2];
    const float* emb_b  = (const float*)d_in[3];
    const float* conv_w = (const float*)d_in[4];
    const float* conv_b = (const float*)d_in[5];
    const float* fc1_w  = (const float*)d_in[6];
    const float* fc1_b  = (const float*)d_in[7];
    const float* fc2_w  = (const float*)d_in[8];
    const float* fc2_b  = (const float*)d_in[9];
    float* out = (float*)d_out;

    int n = in_sizes[0] / 16;
    int E = in_sizes[1] / 2;
    const int* srcI = ei;
    const int* dstI = ei + E;

    // workspace carve-up
    char* w = (char*)d_ws;
    size_t bufBytes = ((size_t)n * NF * sizeof(float) + 255) & ~(size_t)255;
    size_t vecBytes = ((size_t)n * sizeof(float) + 255) & ~(size_t)255;
    float* buf0 = (float*)w; w += bufBytes;
    float* buf2 = (float*)w; w += bufBytes;
    unsigned short* hWb = (unsigned short*)w; w += bufBytes; // bf16 table (uses half)
    float* dis  = (float*)w; w += vecBytes;
    float* dis2 = (float*)w; w += vecBytes;
    float* gsum = (float*)w; w += 256;
    int* cnt    = (int*)w;   w += vecBytes;
    int* excl   = (int*)w;   w += vecBytes;
    int* cursor = (int*)w;   w += vecBytes;
    int* bsum   = (int*)w;   w += 2048;
    int* csr_src= (int*)w;   w += ((size_t)E * sizeof(int) + 255) & ~(size_t)255;

    int nb256 = (n + 255) / 256;

    // CSR build (XCD-partitioned hist + fill)
    init_kernel<<<nb256, 256, 0, stream>>>(cnt, gsum, n);
    deg_hist_kernel<<<1024, 256, 0, stream>>>(dstI, cnt, E, n);
    dis_kernel<<<nb256, 256, 0, stream>>>(cnt, dis, dis2, n);
    scan1_kernel<<<nb256, 256, 0, stream>>>(cnt, excl, bsum, n);
    scan2_kernel<<<1, 512, 0, stream>>>(bsum, nb256);
    scan3_kernel<<<nb256, 256, 0, stream>>>(excl, cursor, bsum, n);
    fill_kernel<<<1024, 256, 0, stream>>>(srcI, dstI, cursor, csr_src, E, n);

    // embedding
    emb_gemm<<<(n + 1) / 2, 256, 0, stream>>>(x, emb_w, emb_b, buf0, n);

    int gemm_grid = (n + BM - 1) / BM;
    int agg_grid = (n + 3) / 4;

    // layer 0: buf0 -> hWb -> buf2
    conv_gemm<<<gemm_grid, 256, 0, stream>>>(buf0, conv_w, hWb, n, 0);
    gather_agg<<<agg_grid, 256, 0, stream>>>(csr_src, excl, cnt, dis, dis2,
                                             hWb, conv_b, buf2, n);
    // layer 1: relu(buf2) -> hWb -> buf0
    conv_gemm<<<gemm_grid, 256, 0, stream>>>(buf2, conv_w + 1 * NF * NF, hWb, n, 1);
    gather_agg<<<agg_grid, 256, 0, stream>>>(csr_src, excl, cnt, dis, dis2,
                                             hWb, conv_b + 1 * NF, buf0, n);
    // layer 2: relu(buf0) -> hWb -> buf2
    conv_gemm<<<gemm_grid, 256, 0, stream>>>(buf0, conv_w + 2 * NF * NF, hWb, n, 1);
    gather_agg<<<agg_grid, 256, 0, stream>>>(csr_src, excl, cnt, dis, dis2,
                                             hWb, conv_b + 2 * NF, buf2, n);

    // global mean of relu(buf2), then MLP head
    mean_kernel<<<512, 256, 0, stream>>>(buf2, gsum, n);
    head_kernel<<<1, 128, 0, stream>>>(gsum, fc1_w, fc1_b, fc2_w, fc2_b, out, n);
}

// Round 5
// 563.123 us; speedup vs baseline: 14.9939x; 1.2350x over previous
//
#include <hip/hip_runtime.h>

#define NF 128   // hidden feature width

typedef short short8 __attribute__((ext_vector_type(8)));
typedef float f32x4 __attribute__((ext_vector_type(4)));

// k-block XOR swizzle for LDS W tiles: keeps 16B alignment, breaks bank conflicts
#define KSW(nn,kk) ((kk) ^ (((nn)&3)<<3))

__device__ __forceinline__ unsigned rne16(float x) {
    unsigned b = __float_as_uint(x);
    return (b + 0x7FFFu + ((b >> 16) & 1u)) >> 16;
}
// pack two fp32 -> two bf16 (RNE) in one uint (lo in low half)
__device__ __forceinline__ unsigned pack2bf(float lo, float hi) {
    unsigned a = __float_as_uint(lo);
    a = (a + 0x7FFFu + ((a >> 16) & 1u)) >> 16;
    unsigned b = __float_as_uint(hi);
    b = (b + 0x7FFFu + ((b >> 16) & 1u)) & 0xFFFF0000u;
    return a | b;
}
// unpack 8 bf16 from uint4, fma into acc[8] with weight w
__device__ __forceinline__ void bf8_fma(uint4 u, float w, float* acc) {
    acc[0] = fmaf(__uint_as_float(u.x << 16), w, acc[0]);
    acc[1] = fmaf(__uint_as_float(u.x & 0xFFFF0000u), w, acc[1]);
    acc[2] = fmaf(__uint_as_float(u.y << 16), w, acc[2]);
    acc[3] = fmaf(__uint_as_float(u.y & 0xFFFF0000u), w, acc[3]);
    acc[4] = fmaf(__uint_as_float(u.z << 16), w, acc[4]);
    acc[5] = fmaf(__uint_as_float(u.z & 0xFFFF0000u), w, acc[5]);
    acc[6] = fmaf(__uint_as_float(u.w << 16), w, acc[6]);
    acc[7] = fmaf(__uint_as_float(u.w & 0xFFFF0000u), w, acc[7]);
}
// relu on two packed bf16 (relu∘RNE == RNE∘relu)
__device__ __forceinline__ unsigned relu2bf(unsigned u) {
    if (u & 0x8000u) u &= 0xFFFF0000u;
    if (u & 0x80000000u) u &= 0x0000FFFFu;
    return u;
}

// ---------------- init ------------------------------------------------------
__global__ void init_kernel(int* cnt, float* gsum, int n) {
    int i = blockIdx.x * blockDim.x + threadIdx.x;
    if (i < n) cnt[i] = 0;
    if (i < NF) gsum[i] = 0.0f;
}

// XCD-partitioned histogram
__global__ __launch_bounds__(256) void deg_hist_kernel(const int* __restrict__ dst,
                                                       int* cnt, int E, int n) {
    int p = blockIdx.x & 7;
    int lo = (int)((long)p * n / 8);
    int hi = (int)((long)(p + 1) * n / 8);
    int stride = (gridDim.x >> 3) * 256;
    for (int e = (blockIdx.x >> 3) * 256 + threadIdx.x; e < E; e += stride) {
        int d = dst[e];
        if (d >= lo && d < hi) atomicAdd(&cnt[d], 1);
    }
}

__global__ void dis_kernel(const int* __restrict__ cnt, float* dis, float* dis2, int n) {
    int i = blockIdx.x * blockDim.x + threadIdx.x;
    if (i >= n) return;
    float d = (float)(cnt[i] + 1);   // +1 self-loop
    dis[i]  = 1.0f / sqrtf(d);
    dis2[i] = 1.0f / d;
}

// ---------------- prefix scan (3 phases) ------------------------------------
__global__ void scan1_kernel(const int* __restrict__ cnt, int* excl, int* bsum, int n) {
    __shared__ int s[256];
    int t = threadIdx.x;
    int i = blockIdx.x * 256 + t;
    int v = (i < n) ? cnt[i] : 0;
    s[t] = v;
    __syncthreads();
    for (int off = 1; off < 256; off <<= 1) {
        int add = (t >= off) ? s[t - off] : 0;
        __syncthreads();
        s[t] += add;
        __syncthreads();
    }
    if (i < n) excl[i] = s[t] - v;
    if (t == 255) bsum[blockIdx.x] = s[255];
}

__global__ void scan2_kernel(int* bsum, int nb) {
    __shared__ int s[512];
    int t = threadIdx.x;
    int v = (t < nb) ? bsum[t] : 0;
    s[t] = v;
    __syncthreads();
    for (int off = 1; off < 512; off <<= 1) {
        int add = (t >= off) ? s[t - off] : 0;
        __syncthreads();
        s[t] += add;
        __syncthreads();
    }
    if (t < nb) bsum[t] = s[t] - v;
}

__global__ void scan3_kernel(int* excl, int* cursor, const int* __restrict__ bsum, int n) {
    int i = blockIdx.x * blockDim.x + threadIdx.x;
    if (i >= n) return;
    int o = excl[i] + bsum[i >> 8];
    excl[i] = o;
    cursor[i] = o;
}

// XCD-partitioned CSR fill
__global__ __launch_bounds__(256) void fill_kernel(const int* __restrict__ src,
                                                   const int* __restrict__ dst,
                                                   int* cursor, int* csr_src,
                                                   int E, int n) {
    int p = blockIdx.x & 7;
    int lo = (int)((long)p * n / 8);
    int hi = (int)((long)(p + 1) * n / 8);
    int stride = (gridDim.x >> 3) * 256;
    for (int e = (blockIdx.x >> 3) * 256 + threadIdx.x; e < E; e += stride) {
        int d = dst[e];
        if (d >= lo && d < hi) {
            int pos = atomicAdd(&cursor[d], 1);
            csr_src[pos] = src[e];
        }
    }
}

// ---------------- weight prep: split W into bf16 hi + bf16 residual, transposed
__global__ void wprep_kernel(const float* __restrict__ W,
                             unsigned short* __restrict__ whi,
                             unsigned short* __restrict__ wre) {
    int idx = blockIdx.x * 256 + threadIdx.x;
    if (idx >= 3 * NF * NF) return;
    int l = idx >> 14;
    int k = (idx >> 7) & 127;
    int c = idx & 127;
    float w = W[idx];
    unsigned hb = rne16(w);
    float hi = __uint_as_float(hb << 16);
    unsigned rb = rne16(w - hi);
    int o = l * 16384 + c * 128 + k;   // [l][n][k] transposed
    whi[o] = (unsigned short)hb;
    wre[o] = (unsigned short)rb;
}

// ---------------- embedding: h(bf16) = x[n,16] @ W[16,128] + b ---------------
__global__ __launch_bounds__(256) void emb_gemm(const float* __restrict__ x,
                                                const float* __restrict__ W,
                                                const float* __restrict__ b,
                                                unsigned short* __restrict__ h, int n) {
    int tid = threadIdx.x;
    int col = tid & (NF - 1);
    int row = blockIdx.x * 2 + (tid >> 7);
    if (row >= n) return;
    const float* xr = x + (size_t)row * 16;
    float acc = b[col];
#pragma unroll
    for (int k = 0; k < 16; ++k) acc = fmaf(xr[k], W[k * NF + col], acc);
    h[(size_t)row * NF + col] = (unsigned short)rne16(acc);
}

// ---------------- conv GEMM via MFMA: hW(bf16) = relu?(A_bf16) @ (Whi+Wre) ---
// block = 4 waves x 16 rows = 64 rows; W tiles staged in LDS transposed [n][k]
__global__ __launch_bounds__(256) void conv_mfma(const unsigned short* __restrict__ A,
                                                 const unsigned short* __restrict__ Whi,
                                                 const unsigned short* __restrict__ Wre,
                                                 unsigned short* __restrict__ hWb,
                                                 int n, int relu_in) {
    __shared__ unsigned short sH[128][72];   // [n][k-local], k swizzled, 144B rows
    __shared__ unsigned short sR[128][72];
    int tid = threadIdx.x;
    int lane = tid & 63, wv = tid >> 6;
    int m = lane & 15, quad = lane >> 4;
    int row0 = blockIdx.x * 64;
    int arow = row0 + wv * 16 + m;
    f32x4 acc[8];
#pragma unroll
    for (int t = 0; t < 8; ++t) acc[t] = (f32x4){0.f, 0.f, 0.f, 0.f};

    for (int kh = 0; kh < 2; ++kh) {
        // stage both W half-tiles: 1024 uint4 chunks each
#pragma unroll
        for (int i = 0; i < 4; ++i) {
            int c = i * 256 + tid;
            int nn = c >> 3, k0 = (c & 7) * 8;
            int g = nn * 128 + kh * 64 + k0;
            *(uint4*)&sH[nn][KSW(nn, k0)] = *(const uint4*)&Whi[g];
            *(uint4*)&sR[nn][KSW(nn, k0)] = *(const uint4*)&Wre[g];
        }
        __syncthreads();
#pragma unroll
        for (int s = 0; s < 2; ++s) {
            int kb = kh * 64 + s * 32 + quad * 8;   // global k base for A frag
            union { uint4 u; short8 v; } af;
            af.u = (uint4){0u, 0u, 0u, 0u};
            if (arow < n) af.u = *(const uint4*)&A[(size_t)arow * NF + kb];
            if (relu_in) {
                af.u.x = relu2bf(af.u.x); af.u.y = relu2bf(af.u.y);
                af.u.z = relu2bf(af.u.z); af.u.w = relu2bf(af.u.w);
            }
            int kl = s * 32 + quad * 8;             // k-local in LDS tile
#pragma unroll
            for (int t = 0; t < 8; ++t) {
                int bn = t * 16 + m;
                union { uint4 u; short8 v; } bh, br;
                bh.u = *(const uint4*)&sH[bn][KSW(bn, kl)];
                br.u = *(const uint4*)&sR[bn][KSW(bn, kl)];
                acc[t] = __builtin_amdgcn_mfma_f32_16x16x32_bf16(af.v, bh.v, acc[t], 0, 0, 0);
                acc[t] = __builtin_amdgcn_mfma_f32_16x16x32_bf16(af.v, br.v, acc[t], 0, 0, 0);
            }
        }
        __syncthreads();
    }
    // epilogue: C/D layout col=lane&15, row=quad*4+reg
    int orow0 = row0 + wv * 16 + quad * 4;
#pragma unroll
    for (int r = 0; r < 4; ++r) {
        int orow = orow0 + r;
        if (orow < n) {
#pragma unroll
            for (int t = 0; t < 8; ++t)
                hWb[(size_t)orow * NF + t * 16 + m] = (unsigned short)rne16(acc[t][r]);
        }
    }
}

// -------- gather aggregate over bf16 hW rows; output bf16 (relu deferred) ----
__global__ __launch_bounds__(256) void gather_agg(const int* __restrict__ csr_src,
                                                  const int* __restrict__ off,
                                                  const int* __restrict__ cnt,
                                                  const float* __restrict__ dis,
                                                  const float* __restrict__ dis2,
                                                  const unsigned short* __restrict__ hWb,
                                                  const float* __restrict__ bias,
                                                  unsigned short* __restrict__ outv, int n) {
    int lane = threadIdx.x & 63;
    int q = lane >> 4;        // quarter 0..3
    int li = lane & 15;       // features [li*8, li*8+8)
    int d = blockIdx.x * 4 + (threadIdx.x >> 6);
    if (d >= n) return;
    int o = off[d];
    int c = cnt[d];
    const uint4* hw = (const uint4*)hWb;   // row = 16 x uint4
    float acc[8] = {};
    int j = q;
    for (; j + 4 < c; j += 8) {
        int s0 = csr_src[o + j];
        int s1 = csr_src[o + j + 4];
        float w0 = dis[s0], w1 = dis[s1];
        uint4 u0 = hw[(size_t)s0 * 16 + li];
        uint4 u1 = hw[(size_t)s1 * 16 + li];
        bf8_fma(u0, w0, acc);
        bf8_fma(u1, w1, acc);
    }
    for (; j < c; j += 4) {
        int s0 = csr_src[o + j];
        float w0 = dis[s0];
        uint4 u0 = hw[(size_t)s0 * 16 + li];
        bf8_fma(u0, w0, acc);
    }
#pragma unroll
    for (int k = 0; k < 8; ++k) {
        acc[k] += __shfl_xor(acc[k], 16);
        acc[k] += __shfl_xor(acc[k], 32);
    }
    if (q == 0) {
        float dd = dis[d], d2 = dis2[d];
        uint4 us = hw[(size_t)d * 16 + li];
        float self[8] = {};
        bf8_fma(us, 1.0f, self);
        const float4* b4 = (const float4*)&bias[li * 8];
        float4 ba = b4[0], bb = b4[1];
        float bk[8] = { ba.x, ba.y, ba.z, ba.w, bb.x, bb.y, bb.z, bb.w };
        float r[8];
#pragma unroll
        for (int k = 0; k < 8; ++k) r[k] = fmaf(acc[k], dd, fmaf(self[k], d2, bk[k]));
        uint4 ov;
        ov.x = pack2bf(r[0], r[1]);
        ov.y = pack2bf(r[2], r[3]);
        ov.z = pack2bf(r[4], r[5]);
        ov.w = pack2bf(r[6], r[7]);
        ((uint4*)outv)[(size_t)d * 16 + li] = ov;
    }
}

// ---------------- mean over nodes of relu(agg bf16) --------------------------
__global__ __launch_bounds__(256) void mean_kernel(const unsigned short* __restrict__ agg,
                                                   float* gsum, int n) {
    int c = threadIdx.x & 63;      // uint index (2 feats)
    int rl = threadIdx.x >> 6;     // 0..3
    float s0 = 0.f, s1 = 0.f;
    const unsigned* a32 = (const unsigned*)agg;
    for (int row = blockIdx.x * 4 + rl; row < n; row += gridDim.x * 4) {
        unsigned u = a32[(size_t)row * 64 + c];
        s0 += fmaxf(__uint_as_float(u << 16), 0.f);
        s1 += fmaxf(__uint_as_float(u & 0xFFFF0000u), 0.f);
    }
    __shared__ float r0[256], r1[256];
    r0[threadIdx.x] = s0;
    r1[threadIdx.x] = s1;
    __syncthreads();
    if (rl == 0) {
#pragma unroll
        for (int j = 1; j < 4; ++j) {
            s0 += r0[threadIdx.x + 64 * j];
            s1 += r1[threadIdx.x + 64 * j];
        }
        atomicAdd(&gsum[2 * c], s0);
        atomicAdd(&gsum[2 * c + 1], s1);
    }
}

// ---------------- head: mean -> fc1+relu -> fc2 ------------------------------
__global__ __launch_bounds__(128) void head_kernel(const float* __restrict__ gsum,
                                                   const float* __restrict__ fc1_w,
                                                   const float* __restrict__ fc1_b,
                                                   const float* __restrict__ fc2_w,
                                                   const float* __restrict__ fc2_b,
                                                   float* __restrict__ out, int n) {
    __shared__ float gm[NF], h1[NF];
    int t = threadIdx.x;
    gm[t] = gsum[t] / (float)n;
    __syncthreads();
    float acc = fc1_b[t];
    for (int k = 0; k < NF; ++k) acc = fmaf(gm[k], fc1_w[k * NF + t], acc);
    h1[t] = fmaxf(acc, 0.f);
    __syncthreads();
    if (t < 64) {
        float o = fc2_b[t];
        for (int k = 0; k < NF; ++k) o = fmaf(h1[k], fc2_w[k * 64 + t], o);
        out[t] = o;
    }
}

extern "C" void kernel_launch(void* const* d_in, const int* in_sizes, int n_in,
                              void* d_out, int out_size, void* d_ws, size_t ws_size,
                              hipStream_t stream) {
    const float* x      = (const float*)d_in[0];
    const int*   ei     = (const int*)  d_in[1];
    const float* emb_w  = (const float*)d_in[2];
    const float* emb_b  = (const float*)d_in[3];
    const float* conv_w = (const float*)d_in[4];
    const float* conv_b = (const float*)d_in[5];
    const float* fc1_w  = (const float*)d_in[6];
    const float* fc1_b  = (const float*)d_in[7];
    const float* fc2_w  = (const float*)d_in[8];
    const float* fc2_b  = (const float*)d_in[9];
    float* out = (float*)d_out;

    int n = in_sizes[0] / 16;
    int E = in_sizes[1] / 2;
    const int* srcI = ei;
    const int* dstI = ei + E;

    // workspace carve-up (bf16 node buffers)
    char* w = (char*)d_ws;
    size_t bufBytes = ((size_t)n * NF * 2 + 255) & ~(size_t)255;
    size_t vecBytes = ((size_t)n * sizeof(float) + 255) & ~(size_t)255;
    unsigned short* buf0 = (unsigned short*)w; w += bufBytes;
    unsigned short* buf2 = (unsigned short*)w; w += bufBytes;
    unsigned short* hWb  = (unsigned short*)w; w += bufBytes;
    unsigned short* whi  = (unsigned short*)w; w += (3 * NF * NF * 2 + 256);
    unsigned short* wre  = (unsigned short*)w; w += (3 * NF * NF * 2 + 256);
    float* dis  = (float*)w; w += vecBytes;
    float* dis2 = (float*)w; w += vecBytes;
    float* gsum = (float*)w; w += 256;
    int* cnt    = (int*)w;   w += vecBytes;
    int* excl   = (int*)w;   w += vecBytes;
    int* cursor = (int*)w;   w += vecBytes;
    int* bsum   = (int*)w;   w += 2048;
    int* csr_src= (int*)w;   w += ((size_t)E * sizeof(int) + 255) & ~(size_t)255;

    int nb256 = (n + 255) / 256;

    // CSR build (XCD-partitioned hist + fill, bigger grids for latency hiding)
    init_kernel<<<nb256, 256, 0, stream>>>(cnt, gsum, n);
    deg_hist_kernel<<<4096, 256, 0, stream>>>(dstI, cnt, E, n);
    dis_kernel<<<nb256, 256, 0, stream>>>(cnt, dis, dis2, n);
    scan1_kernel<<<nb256, 256, 0, stream>>>(cnt, excl, bsum, n);
    scan2_kernel<<<1, 512, 0, stream>>>(bsum, nb256);
    scan3_kernel<<<nb256, 256, 0, stream>>>(excl, cursor, bsum, n);
    fill_kernel<<<4096, 256, 0, stream>>>(srcI, dstI, cursor, csr_src, E, n);

    // weight prep + embedding
    wprep_kernel<<<(3 * NF * NF + 255) / 256, 256, 0, stream>>>(conv_w, whi, wre);
    emb_gemm<<<(n + 1) / 2, 256, 0, stream>>>(x, emb_w, emb_b, buf0, n);

    int gemm_grid = (n + 63) / 64;
    int agg_grid = (n + 3) / 4;

    // layer 0: buf0 -> hWb -> buf2
    conv_mfma<<<gemm_grid, 256, 0, stream>>>(buf0, whi, wre, hWb, n, 0);
    gather_agg<<<agg_grid, 256, 0, stream>>>(csr_src, excl, cnt, dis, dis2,
                                             hWb, conv_b, buf2, n);
    // layer 1: relu(buf2) -> hWb -> buf0
    conv_mfma<<<gemm_grid, 256, 0, stream>>>(buf2, whi + NF * NF, wre + NF * NF,
                                             hWb, n, 1);
    gather_agg<<<agg_grid, 256, 0, stream>>>(csr_src, excl, cnt, dis, dis2,
                                             hWb, conv_b + NF, buf0, n);
    // layer 2: relu(buf0) -> hWb -> buf2
    conv_mfma<<<gemm_grid, 256, 0, stream>>>(buf0, whi + 2 * NF * NF, wre + 2 * NF * NF,
                                             hWb, n, 1);
    gather_agg<<<agg_grid, 256, 0, stream>>>(csr_src, excl, cnt, dis, dis2,
                                             hWb, conv_b + 2 * NF, buf2, n);

    // global mean of relu(buf2), then MLP head
    mean_kernel<<<512, 256, 0, stream>>>(buf2, gsum, n);
    head_kernel<<<1, 128, 0, stream>>>(gsum, fc1_w, fc1_b, fc2_w, fc2_b, out, n);
}

// Round 6
// 529.180 us; speedup vs baseline: 15.9556x; 1.0641x over previous
//
#include <hip/hip_runtime.h>

#define NF 128   // hidden feature width

typedef short short8 __attribute__((ext_vector_type(8)));
typedef float f32x4 __attribute__((ext_vector_type(4)));
typedef float f32x2 __attribute__((ext_vector_type(2)));

// k-block XOR swizzle for LDS W tiles
#define KSW(nn,kk) ((kk) ^ (((nn)&3)<<3))

__device__ __forceinline__ unsigned rne16(float x) {
    unsigned b = __float_as_uint(x);
    return (b + 0x7FFFu + ((b >> 16) & 1u)) >> 16;
}
__device__ __forceinline__ unsigned pack2bf(float lo, float hi) {
    unsigned a = __float_as_uint(lo);
    a = (a + 0x7FFFu + ((a >> 16) & 1u)) >> 16;
    unsigned b = __float_as_uint(hi);
    b = (b + 0x7FFFu + ((b >> 16) & 1u)) & 0xFFFF0000u;
    return a | b;
}
// unpack 8 fp8(e4m3) from uint2, fma into acc[8] with weight w
__device__ __forceinline__ void fp8x8_fma(uint2 u, float w, float* acc) {
    f32x2 g0 = __builtin_amdgcn_cvt_pk_f32_fp8((int)u.x, false);
    f32x2 g1 = __builtin_amdgcn_cvt_pk_f32_fp8((int)u.x, true);
    f32x2 g2 = __builtin_amdgcn_cvt_pk_f32_fp8((int)u.y, false);
    f32x2 g3 = __builtin_amdgcn_cvt_pk_f32_fp8((int)u.y, true);
    acc[0] = fmaf(g0.x, w, acc[0]); acc[1] = fmaf(g0.y, w, acc[1]);
    acc[2] = fmaf(g1.x, w, acc[2]); acc[3] = fmaf(g1.y, w, acc[3]);
    acc[4] = fmaf(g2.x, w, acc[4]); acc[5] = fmaf(g2.y, w, acc[5]);
    acc[6] = fmaf(g3.x, w, acc[6]); acc[7] = fmaf(g3.y, w, acc[7]);
}
// pack 4 fp32 -> 4 fp8 in one uint
__device__ __forceinline__ unsigned pack4fp8(float a, float b, float c, float d) {
    int u = __builtin_amdgcn_cvt_pk_fp8_f32(a, b, 0, false);
    u = __builtin_amdgcn_cvt_pk_fp8_f32(c, d, u, true);
    return (unsigned)u;
}
// relu on two packed bf16
__device__ __forceinline__ unsigned relu2bf(unsigned u) {
    if (u & 0x8000u) u &= 0xFFFF0000u;
    if (u & 0x80000000u) u &= 0x0000FFFFu;
    return u;
}

// ---------------- init ------------------------------------------------------
__global__ void init_kernel(int* cnt, float* gsum, int n) {
    int i = blockIdx.x * blockDim.x + threadIdx.x;
    if (i < n) cnt[i] = 0;
    if (i < NF) gsum[i] = 0.0f;
}

// XCD-partitioned histogram
__global__ __launch_bounds__(256) void deg_hist_kernel(const int* __restrict__ dst,
                                                       int* cnt, int E, int n) {
    int p = blockIdx.x & 7;
    int lo = (int)((long)p * n / 8);
    int hi = (int)((long)(p + 1) * n / 8);
    int stride = (gridDim.x >> 3) * 256;
    for (int e = (blockIdx.x >> 3) * 256 + threadIdx.x; e < E; e += stride) {
        int d = dst[e];
        if (d >= lo && d < hi) atomicAdd(&cnt[d], 1);
    }
}

__global__ void dis_kernel(const int* __restrict__ cnt, float* dis, float* dis2, int n) {
    int i = blockIdx.x * blockDim.x + threadIdx.x;
    if (i >= n) return;
    float d = (float)(cnt[i] + 1);   // +1 self-loop
    dis[i]  = 1.0f / sqrtf(d);
    dis2[i] = 1.0f / d;
}

// ---------------- prefix scan (3 phases) ------------------------------------
__global__ void scan1_kernel(const int* __restrict__ cnt, int* excl, int* bsum, int n) {
    __shared__ int s[256];
    int t = threadIdx.x;
    int i = blockIdx.x * 256 + t;
    int v = (i < n) ? cnt[i] : 0;
    s[t] = v;
    __syncthreads();
    for (int off = 1; off < 256; off <<= 1) {
        int add = (t >= off) ? s[t - off] : 0;
        __syncthreads();
        s[t] += add;
        __syncthreads();
    }
    if (i < n) excl[i] = s[t] - v;
    if (t == 255) bsum[blockIdx.x] = s[255];
}

__global__ void scan2_kernel(int* bsum, int nb) {
    __shared__ int s[512];
    int t = threadIdx.x;
    int v = (t < nb) ? bsum[t] : 0;
    s[t] = v;
    __syncthreads();
    for (int off = 1; off < 512; off <<= 1) {
        int add = (t >= off) ? s[t - off] : 0;
        __syncthreads();
        s[t] += add;
        __syncthreads();
    }
    if (t < nb) bsum[t] = s[t] - v;
}

__global__ void scan3_kernel(int* excl, int* cursor, const int* __restrict__ bsum, int n) {
    int i = blockIdx.x * blockDim.x + threadIdx.x;
    if (i >= n) return;
    int o = excl[i] + bsum[i >> 8];
    excl[i] = o;
    cursor[i] = o;
}

// XCD-partitioned CSR fill
__global__ __launch_bounds__(256) void fill_kernel(const int* __restrict__ src,
                                                   const int* __restrict__ dst,
                                                   int* cursor, int* csr_src,
                                                   int E, int n) {
    int p = blockIdx.x & 7;
    int lo = (int)((long)p * n / 8);
    int hi = (int)((long)(p + 1) * n / 8);
    int stride = (gridDim.x >> 3) * 256;
    for (int e = (blockIdx.x >> 3) * 256 + threadIdx.x; e < E; e += stride) {
        int d = dst[e];
        if (d >= lo && d < hi) {
            int pos = atomicAdd(&cursor[d], 1);
            csr_src[pos] = src[e];
        }
    }
}

// ---------------- weight prep: split W into bf16 hi + bf16 residual, transposed
__global__ void wprep_kernel(const float* __restrict__ W,
                             unsigned short* __restrict__ whi,
                             unsigned short* __restrict__ wre) {
    int idx = blockIdx.x * 256 + threadIdx.x;
    if (idx >= 3 * NF * NF) return;
    int l = idx >> 14;
    int k = (idx >> 7) & 127;
    int c = idx & 127;
    float w = W[idx];
    unsigned hb = rne16(w);
    float hi = __uint_as_float(hb << 16);
    unsigned rb = rne16(w - hi);
    int o = l * 16384 + c * 128 + k;   // [l][n][k] transposed
    whi[o] = (unsigned short)hb;
    wre[o] = (unsigned short)rb;
}

// ---------------- embedding: h(bf16) = x[n,16] @ W[16,128] + b ---------------
__global__ __launch_bounds__(256) void emb_gemm(const float* __restrict__ x,
                                                const float* __restrict__ W,
                                                const float* __restrict__ b,
                                                unsigned short* __restrict__ h, int n) {
    int tid = threadIdx.x;
    int col = tid & (NF - 1);
    int row = blockIdx.x * 2 + (tid >> 7);
    if (row >= n) return;
    const float* xr = x + (size_t)row * 16;
    float acc = b[col];
#pragma unroll
    for (int k = 0; k < 16; ++k) acc = fmaf(xr[k], W[k * NF + col], acc);
    h[(size_t)row * NF + col] = (unsigned short)rne16(acc);
}

// ---------------- conv GEMM via MFMA: hW(fp8) = relu?(A_bf16) @ (Whi+Wre) ----
// 4 waves x 16 rows = 64 rows/block; W tiles in LDS transposed [n][k];
// epilogue stages fp32 C through LDS (reusing W-tile space) to pack fp8 rows
__global__ __launch_bounds__(256) void conv_mfma(const unsigned short* __restrict__ A,
                                                 const unsigned short* __restrict__ Whi,
                                                 const unsigned short* __restrict__ Wre,
                                                 unsigned char* __restrict__ hW8,
                                                 int n, int relu_in) {
    __shared__ unsigned char smem[36864];
    unsigned short (*sH)[72] = (unsigned short (*)[72])smem;            // 18432 B
    unsigned short (*sR)[72] = (unsigned short (*)[72])(smem + 18432);  // 18432 B
    int tid = threadIdx.x;
    int lane = tid & 63, wv = tid >> 6;
    int m = lane & 15, quad = lane >> 4;
    int row0 = blockIdx.x * 64;
    int arow = row0 + wv * 16 + m;
    f32x4 acc[8];
#pragma unroll
    for (int t = 0; t < 8; ++t) acc[t] = (f32x4){0.f, 0.f, 0.f, 0.f};

    for (int kh = 0; kh < 2; ++kh) {
#pragma unroll
        for (int i = 0; i < 4; ++i) {
            int c = i * 256 + tid;
            int nn = c >> 3, k0 = (c & 7) * 8;
            int g = nn * 128 + kh * 64 + k0;
            *(uint4*)&sH[nn][KSW(nn, k0)] = *(const uint4*)&Whi[g];
            *(uint4*)&sR[nn][KSW(nn, k0)] = *(const uint4*)&Wre[g];
        }
        __syncthreads();
#pragma unroll
        for (int s = 0; s < 2; ++s) {
            int kb = kh * 64 + s * 32 + quad * 8;
            union { uint4 u; short8 v; } af;
            af.u = (uint4){0u, 0u, 0u, 0u};
            if (arow < n) af.u = *(const uint4*)&A[(size_t)arow * NF + kb];
            if (relu_in) {
                af.u.x = relu2bf(af.u.x); af.u.y = relu2bf(af.u.y);
                af.u.z = relu2bf(af.u.z); af.u.w = relu2bf(af.u.w);
            }
            int kl = s * 32 + quad * 8;
#pragma unroll
            for (int t = 0; t < 8; ++t) {
                int bn = t * 16 + m;
                union { uint4 u; short8 v; } bh, br;
                bh.u = *(const uint4*)&sH[bn][KSW(bn, kl)];
                br.u = *(const uint4*)&sR[bn][KSW(bn, kl)];
                acc[t] = __builtin_amdgcn_mfma_f32_16x16x32_bf16(af.v, bh.v, acc[t], 0, 0, 0);
                acc[t] = __builtin_amdgcn_mfma_f32_16x16x32_bf16(af.v, br.v, acc[t], 0, 0, 0);
            }
        }
        __syncthreads();
    }
    // epilogue: C layout col=m, row=quad*4+r. Stage fp32 to LDS, repack fp8.
    float* sOut = (float*)smem;   // [64][132] floats = 33792 B, overlays sH/sR
#pragma unroll
    for (int r = 0; r < 4; ++r) {
        int lrow = wv * 16 + quad * 4 + r;
#pragma unroll
        for (int t = 0; t < 8; ++t)
            sOut[lrow * 132 + t * 16 + m] = acc[t][r];
    }
    __syncthreads();
#pragma unroll
    for (int it = 0; it < 2; ++it) {
        int lrow = it * 32 + (tid >> 3);
        int grow = row0 + lrow;
        int c0 = (tid & 7) * 16;
        if (grow < n) {
            const float* p = &sOut[lrow * 132 + c0];
            uint4 o;
            o.x = pack4fp8(p[0],  p[1],  p[2],  p[3]);
            o.y = pack4fp8(p[4],  p[5],  p[6],  p[7]);
            o.z = pack4fp8(p[8],  p[9],  p[10], p[11]);
            o.w = pack4fp8(p[12], p[13], p[14], p[15]);
            *(uint4*)&hW8[(size_t)grow * NF + c0] = o;
        }
    }
}

// -------- gather aggregate over fp8 hW rows (128B = 16 lanes x uint2) --------
// one wave per node; quarter-wave per row; 4 rows x 2-deep unroll in flight
__global__ __launch_bounds__(256) void gather_agg(const int* __restrict__ csr_src,
                                                  const int* __restrict__ off,
                                                  const int* __restrict__ cnt,
                                                  const float* __restrict__ dis,
                                                  const float* __restrict__ dis2,
                                                  const unsigned char* __restrict__ hW8,
                                                  const float* __restrict__ bias,
                                                  unsigned short* __restrict__ outv, int n) {
    int lane = threadIdx.x & 63;
    int q = lane >> 4;        // quarter 0..3
    int li = lane & 15;       // features [li*8, li*8+8)
    int d = blockIdx.x * 4 + (threadIdx.x >> 6);
    if (d >= n) return;
    int o = off[d];
    int c = cnt[d];
    const uint2* hw = (const uint2*)hW8;   // row = 16 x uint2 (128 B)
    float acc[8] = {};
    int j = q;
    for (; j + 4 < c; j += 8) {
        int s0 = csr_src[o + j];
        int s1 = csr_src[o + j + 4];
        float w0 = dis[s0], w1 = dis[s1];
        uint2 u0 = hw[(size_t)s0 * 16 + li];
        uint2 u1 = hw[(size_t)s1 * 16 + li];
        fp8x8_fma(u0, w0, acc);
        fp8x8_fma(u1, w1, acc);
    }
    for (; j < c; j += 4) {
        int s0 = csr_src[o + j];
        float w0 = dis[s0];
        uint2 u0 = hw[(size_t)s0 * 16 + li];
        fp8x8_fma(u0, w0, acc);
    }
#pragma unroll
    for (int k = 0; k < 8; ++k) {
        acc[k] += __shfl_xor(acc[k], 16);
        acc[k] += __shfl_xor(acc[k], 32);
    }
    if (q == 0) {
        float dd = dis[d], d2 = dis2[d];
        uint2 us = hw[(size_t)d * 16 + li];
        float self[8] = {};
        fp8x8_fma(us, 1.0f, self);
        const float4* b4 = (const float4*)&bias[li * 8];
        float4 ba = b4[0], bb = b4[1];
        float bk[8] = { ba.x, ba.y, ba.z, ba.w, bb.x, bb.y, bb.z, bb.w };
        float r[8];
#pragma unroll
        for (int k = 0; k < 8; ++k) r[k] = fmaf(acc[k], dd, fmaf(self[k], d2, bk[k]));
        uint4 ov;
        ov.x = pack2bf(r[0], r[1]);
        ov.y = pack2bf(r[2], r[3]);
        ov.z = pack2bf(r[4], r[5]);
        ov.w = pack2bf(r[6], r[7]);
        ((uint4*)outv)[(size_t)d * 16 + li] = ov;
    }
}

// ---------------- mean over nodes of relu(agg bf16) --------------------------
__global__ __launch_bounds__(256) void mean_kernel(const unsigned short* __restrict__ agg,
                                                   float* gsum, int n) {
    int c = threadIdx.x & 63;
    int rl = threadIdx.x >> 6;
    float s0 = 0.f, s1 = 0.f;
    const unsigned* a32 = (const unsigned*)agg;
    for (int row = blockIdx.x * 4 + rl; row < n; row += gridDim.x * 4) {
        unsigned u = a32[(size_t)row * 64 + c];
        s0 += fmaxf(__uint_as_float(u << 16), 0.f);
        s1 += fmaxf(__uint_as_float(u & 0xFFFF0000u), 0.f);
    }
    __shared__ float r0[256], r1[256];
    r0[threadIdx.x] = s0;
    r1[threadIdx.x] = s1;
    __syncthreads();
    if (rl == 0) {
#pragma unroll
        for (int j = 1; j < 4; ++j) {
            s0 += r0[threadIdx.x + 64 * j];
            s1 += r1[threadIdx.x + 64 * j];
        }
        atomicAdd(&gsum[2 * c], s0);
        atomicAdd(&gsum[2 * c + 1], s1);
    }
}

// ---------------- head: mean -> fc1+relu -> fc2 ------------------------------
__global__ __launch_bounds__(128) void head_kernel(const float* __restrict__ gsum,
                                                   const float* __restrict__ fc1_w,
                                                   const float* __restrict__ fc1_b,
                                                   const float* __restrict__ fc2_w,
                                                   const float* __restrict__ fc2_b,
                                                   float* __restrict__ out, int n) {
    __shared__ float gm[NF], h1[NF];
    int t = threadIdx.x;
    gm[t] = gsum[t] / (float)n;
    __syncthreads();
    float acc = fc1_b[t];
    for (int k = 0; k < NF; ++k) acc = fmaf(gm[k], fc1_w[k * NF + t], acc);
    h1[t] = fmaxf(acc, 0.f);
    __syncthreads();
    if (t < 64) {
        float o = fc2_b[t];
        for (int k = 0; k < NF; ++k) o = fmaf(h1[k], fc2_w[k * 64 + t], o);
        out[t] = o;
    }
}

extern "C" void kernel_launch(void* const* d_in, const int* in_sizes, int n_in,
                              void* d_out, int out_size, void* d_ws, size_t ws_size,
                              hipStream_t stream) {
    const float* x      = (const float*)d_in[0];
    const int*   ei     = (const int*)  d_in[1];
    const float* emb_w  = (const float*)d_in[2];
    const float* emb_b  = (const float*)d_in[3];
    const float* conv_w = (const float*)d_in[4];
    const float* conv_b = (const float*)d_in[5];
    const float* fc1_w  = (const float*)d_in[6];
    const float* fc1_b  = (const float*)d_in[7];
    const float* fc2_w  = (const float*)d_in[8];
    const float* fc2_b  = (const float*)d_in[9];
    float* out = (float*)d_out;

    int n = in_sizes[0] / 16;
    int E = in_sizes[1] / 2;
    const int* srcI = ei;
    const int* dstI = ei + E;

    // workspace carve-up
    char* w = (char*)d_ws;
    size_t bufBytes  = ((size_t)n * NF * 2 + 255) & ~(size_t)255;   // bf16 node buf
    size_t buf8Bytes = ((size_t)n * NF + 255) & ~(size_t)255;       // fp8 table
    size_t vecBytes  = ((size_t)n * sizeof(float) + 255) & ~(size_t)255;
    unsigned short* buf0 = (unsigned short*)w; w += bufBytes;
    unsigned short* buf2 = (unsigned short*)w; w += bufBytes;
    unsigned char*  hW8  = (unsigned char*)w;  w += buf8Bytes;
    unsigned short* whi  = (unsigned short*)w; w += (3 * NF * NF * 2 + 256);
    unsigned short* wre  = (unsigned short*)w; w += (3 * NF * NF * 2 + 256);
    float* dis  = (float*)w; w += vecBytes;
    float* dis2 = (float*)w; w += vecBytes;
    float* gsum = (float*)w; w += 256;
    int* cnt    = (int*)w;   w += vecBytes;
    int* excl   = (int*)w;   w += vecBytes;
    int* cursor = (int*)w;   w += vecBytes;
    int* bsum   = (int*)w;   w += 2048;
    int* csr_src= (int*)w;   w += ((size_t)E * sizeof(int) + 255) & ~(size_t)255;

    int nb256 = (n + 255) / 256;

    // CSR build
    init_kernel<<<nb256, 256, 0, stream>>>(cnt, gsum, n);
    deg_hist_kernel<<<4096, 256, 0, stream>>>(dstI, cnt, E, n);
    dis_kernel<<<nb256, 256, 0, stream>>>(cnt, dis, dis2, n);
    scan1_kernel<<<nb256, 256, 0, stream>>>(cnt, excl, bsum, n);
    scan2_kernel<<<1, 512, 0, stream>>>(bsum, nb256);
    scan3_kernel<<<nb256, 256, 0, stream>>>(excl, cursor, bsum, n);
    fill_kernel<<<4096, 256, 0, stream>>>(srcI, dstI, cursor, csr_src, E, n);

    // weight prep + embedding
    wprep_kernel<<<(3 * NF * NF + 255) / 256, 256, 0, stream>>>(conv_w, whi, wre);
    emb_gemm<<<(n + 1) / 2, 256, 0, stream>>>(x, emb_w, emb_b, buf0, n);

    int gemm_grid = (n + 63) / 64;
    int agg_grid = (n + 3) / 4;

    // layer 0: buf0 -> hW8 -> buf2
    conv_mfma<<<gemm_grid, 256, 0, stream>>>(buf0, whi, wre, hW8, n, 0);
    gather_agg<<<agg_grid, 256, 0, stream>>>(csr_src, excl, cnt, dis, dis2,
                                             hW8, conv_b, buf2, n);
    // layer 1: relu(buf2) -> hW8 -> buf0
    conv_mfma<<<gemm_grid, 256, 0, stream>>>(buf2, whi + NF * NF, wre + NF * NF,
                                             hW8, n, 1);
    gather_agg<<<agg_grid, 256, 0, stream>>>(csr_src, excl, cnt, dis, dis2,
                                             hW8, conv_b + NF, buf0, n);
    // layer 2: relu(buf0) -> hW8 -> buf2
    conv_mfma<<<gemm_grid, 256, 0, stream>>>(buf0, whi + 2 * NF * NF, wre + 2 * NF * NF,
                                             hW8, n, 1);
    gather_agg<<<agg_grid, 256, 0, stream>>>(csr_src, excl, cnt, dis, dis2,
                                             hW8, conv_b + 2 * NF, buf2, n);

    // global mean of relu(buf2), then MLP head
    mean_kernel<<<512, 256, 0, stream>>>(buf2, gsum, n);
    head_kernel<<<1, 128, 0, stream>>>(gsum, fc1_w, fc1_b, fc2_w, fc2_b, out, n);
}